// Round 2
// baseline (1486.916 us; speedup 1.0000x reference)
//
#include <hip/hip_runtime.h>
#include <hip/hip_bf16.h>
#include <stdint.h>

// Problem: h_t = Lam @ h_{t-1} + B @ x_t ; BS=16, T=4096, D=256, fp32 in/out.
// Two-level chunked scan: level-1 chunks c=64, level-2 superchunks of 8.
// R4: fix R3's regression — __launch_bounds__(256,2) capped mega at 128 VGPRs
// and spilled the scan's persistent Lam fragments (bf[8][4] = 128 VGPRs) to
// scratch, slowing the serial chain 6x. Now (256,3): cap 168 >= 148 needed,
// 3 blocks/CU guaranteed -> grid 768 (256 scan + 512 pow blocks, all
// co-resident), doubling pow-phase parallelism.

#define CHUNK 64
#define NPB   512   // pow-group block count

typedef short v8s __attribute__((ext_vector_type(8)));   // 8 x bf16 (4 VGPRs)
typedef float v4f __attribute__((ext_vector_type(4)));   // MFMA accum

static __device__ __forceinline__ unsigned short f2u(float f) {
  union { float f; unsigned int u; } x; x.f = f;
  unsigned int u = x.u + 0x7FFFu + ((x.u >> 16) & 1u);   // RNE f32->bf16
  return (unsigned short)(u >> 16);
}
static __device__ __forceinline__ float u2f(unsigned short h) {
  union { unsigned int u; float f; } x; x.u = ((unsigned int)h) << 16;
  return x.f;
}
// Workgroup barrier that only drains LDS (lgkmcnt), leaving vmcnt free-running
// so register prefetch loads survive across it.
static __device__ __forceinline__ void lds_barrier() {
  asm volatile("s_waitcnt lgkmcnt(0)\n\ts_barrier" ::: "memory");
}
// Device-scope barrier among the NPB pow-group blocks. One counter per phase
// (no reset during the kernel -> no reset race); counters are zeroed by
// pack_init at the head of every launch/replay. All threads fence (release)
// before arrival; thread 0 fences (acquire) after the spin.
static __device__ __forceinline__ void gbar(unsigned* c) {
  __threadfence();
  __syncthreads();
  if (threadIdx.x == 0) {
    atomicAdd(c, 1u);
    while (__hip_atomic_load(c, __ATOMIC_RELAXED, __HIP_MEMORY_SCOPE_AGENT) < NPB)
      __builtin_amdgcn_s_sleep(2);
    __threadfence();
  }
  __syncthreads();
}

// ---------------------------------------------------------------------------
// Generic 64x64-tile bf16 MFMA GEMM. A: f32 or bf16 row-major [M,K] (lda).
// B: bf16 row-major [K,N] (ldb). C: f32 or bf16 [M,N] (ldc).
// blockIdx = (n_tile, m_tile, k_split). Per-split K length = Kper.
// Split partials go to C + z*csplit (f32 path only). ADD_C: C += A*B (f32).
// ---------------------------------------------------------------------------
template<bool A_F32, bool C_BF16, bool ADD_C>
__global__ __launch_bounds__(256) void gemm_tile(
    const void* __restrict__ Ap, const unsigned short* __restrict__ Bp,
    void* __restrict__ Cp, int lda, int ldb, int ldc, int Kper, long csplit)
{
  __shared__ unsigned short As[64][72];   // [m][k], pad to kill bank conflicts
  __shared__ unsigned short Bst[64][72];  // [n][k] (transposed for b128 frag reads)
  const int tid = threadIdx.x;
  const int lane = tid & 63, w = tid >> 6;       // 4 waves
  const int q = lane >> 4, ln = lane & 15;
  const long n0 = (long)blockIdx.x * 64;
  const long m0 = (long)blockIdx.y * 64;
  const int  kz = blockIdx.z;
  const long kbase = (long)kz * Kper;
  const int sm = tid >> 2;          // staging row 0..63
  const int sk = (tid & 3) << 4;    // staging col 0,16,32,48

  v4f acc[4];
#pragma unroll
  for (int i = 0; i < 4; ++i) acc[i] = 0;

  for (int ks = 0; ks < Kper; ks += 64) {
    const long kg = kbase + ks;
    __syncthreads();
    if (A_F32) {
      const float* A = (const float*)Ap + (m0 + sm) * (long)lda + kg + sk;
      float4 f[4];
#pragma unroll
      for (int t = 0; t < 4; ++t) f[t] = ((const float4*)A)[t];
      unsigned short* d = &As[sm][sk];
#pragma unroll
      for (int t = 0; t < 4; ++t) {
        d[4*t+0] = f2u(f[t].x); d[4*t+1] = f2u(f[t].y);
        d[4*t+2] = f2u(f[t].z); d[4*t+3] = f2u(f[t].w);
      }
    } else {
      const unsigned short* A = (const unsigned short*)Ap + (m0 + sm) * (long)lda + kg + sk;
      v8s t0 = ((const v8s*)A)[0], t1 = ((const v8s*)A)[1];
      *(v8s*)&As[sm][sk] = t0; *(v8s*)&As[sm][sk + 8] = t1;
    }
    // stage B (transpose into [n][k])
    {
      const unsigned short* Bg = Bp + (kg + sm) * (long)ldb + n0 + sk;
      v8s b0 = ((const v8s*)Bg)[0], b1 = ((const v8s*)Bg)[1];
#pragma unroll
      for (int r = 0; r < 8; ++r) Bst[sk + r][sm] = (unsigned short)b0[r];
#pragma unroll
      for (int r = 0; r < 8; ++r) Bst[sk + 8 + r][sm] = (unsigned short)b1[r];
    }
    __syncthreads();
#pragma unroll
    for (int kb = 0; kb < 64; kb += 32) {
      v8s a = *(const v8s*)&As[w*16 + ln][kb + q*8];
#pragma unroll
      for (int nb = 0; nb < 4; ++nb) {
        v8s b = *(const v8s*)&Bst[nb*16 + ln][kb + q*8];
        acc[nb] = __builtin_amdgcn_mfma_f32_16x16x32_bf16(a, b, acc[nb], 0, 0, 0);
      }
    }
  }
#pragma unroll
  for (int nb = 0; nb < 4; ++nb)
#pragma unroll
    for (int r = 0; r < 4; ++r) {
      const long row = m0 + w*16 + q*4 + r;        // D row = 4q+r within wave's 16
      const long col = n0 + nb*16 + ln;
      float v = acc[nb][r];
      if (C_BF16) ((unsigned short*)Cp)[row * (long)ldc + col] = f2u(v);
      else {
        float* Cf = (float*)Cp + (long)kz * csplit;
        if (ADD_C) v += Cf[row * (long)ldc + col];
        Cf[row * (long)ldc + col] = v;
      }
    }
}

// ---------------------------------------------------------------------------
// pack_init: Bt[e][d]=B[d][e], LamT[e][d]=Lam[d][e] (bf16); P_0=I, P_1=Lam hi/lo.
// Also zeroes the mega-kernel barrier counters (replay-safe).
// ---------------------------------------------------------------------------
__global__ __launch_bounds__(256) void pack_init(
    const float* __restrict__ Bm, const float* __restrict__ Lam,
    unsigned short* __restrict__ Bt, unsigned short* __restrict__ LamT,
    unsigned short* __restrict__ Phi, unsigned short* __restrict__ Plo,
    unsigned int* __restrict__ cnt)
{
  if (blockIdx.x == 0 && threadIdx.x < 16) cnt[threadIdx.x] = 0;
  const int idx = blockIdx.x * 256 + threadIdx.x;  // 0..65535
  const int e = idx >> 8, d = idx & 255;
  Bt[idx]   = f2u(Bm[d * 256 + e]);
  LamT[idx] = f2u(Lam[d * 256 + e]);
  float v = Lam[idx];                              // idx as (dd,ee) row-major
  unsigned short hi = f2u(v);
  Phi[65536 + idx] = hi;
  Plo[65536 + idx] = f2u(v - u2f(hi));
  const int dd = idx >> 8, ee = idx & 255;
  Phi[idx] = (dd == ee) ? (unsigned short)0x3F80 : (unsigned short)0;
  Plo[idx] = 0;
}

// ---------------------------------------------------------------------------
// Pow-job: P_{mpow+jj} = P_mpow * P_jj, split-bf16 (hi+lo):
// acc = Ah*Bh + Al*Bh + Ah*Bl (drops lo*lo) -> ~fp32. One 64x64 output tile.
// job encodes (jj, n0, m0); jobs per round = 16*mpow.
// ---------------------------------------------------------------------------
static __device__ void pow_job(unsigned short* __restrict__ Phi,
                               unsigned short* __restrict__ Plo,
                               int mpow, int job, char* smem)
{
  unsigned short (*As)[72]  = (unsigned short(*)[72])smem;
  unsigned short (*Bst)[72] = (unsigned short(*)[72])(smem + 9216);
  const int tid = threadIdx.x, lane = tid & 63, w = tid >> 6;
  const int q = lane >> 4, ln = lane & 15;
  const int jj = (job >> 4) + 1;
  const int n0 = (job & 3) * 64;
  const int m0 = ((job >> 2) & 3) * 64;
  const unsigned short* Ah = Phi + (size_t)mpow * 65536;
  const unsigned short* Al = Plo + (size_t)mpow * 65536;
  const unsigned short* Bh = Phi + (size_t)jj * 65536;
  const unsigned short* Bl = Plo + (size_t)jj * 65536;
  const int sm = tid >> 2, sk = (tid & 3) << 4;
  v4f acc[4];
#pragma unroll
  for (int i = 0; i < 4; ++i) acc[i] = 0;

  for (int seg = 0; seg < 3; ++seg) {
    const unsigned short* Asrc = (seg == 1) ? Al : Ah;
    const unsigned short* Bsrc = (seg == 2) ? Bl : Bh;
    for (int ks = 0; ks < 256; ks += 64) {
      __syncthreads();
      {
        const unsigned short* Ag = Asrc + (size_t)(m0 + sm) * 256 + ks + sk;
        v8s t0 = ((const v8s*)Ag)[0], t1 = ((const v8s*)Ag)[1];
        *(v8s*)&As[sm][sk] = t0; *(v8s*)&As[sm][sk + 8] = t1;
      }
      {
        const unsigned short* Bg = Bsrc + (size_t)(ks + sm) * 256 + n0 + sk;
        v8s b0 = ((const v8s*)Bg)[0], b1 = ((const v8s*)Bg)[1];
#pragma unroll
        for (int r = 0; r < 8; ++r) Bst[sk + r][sm] = (unsigned short)b0[r];
#pragma unroll
        for (int r = 0; r < 8; ++r) Bst[sk + 8 + r][sm] = (unsigned short)b1[r];
      }
      __syncthreads();
#pragma unroll
      for (int kb = 0; kb < 64; kb += 32) {
        v8s a = *(const v8s*)&As[w*16 + ln][kb + q*8];
#pragma unroll
        for (int nb = 0; nb < 4; ++nb) {
          v8s bb = *(const v8s*)&Bst[nb*16 + ln][kb + q*8];
          acc[nb] = __builtin_amdgcn_mfma_f32_16x16x32_bf16(a, bb, acc[nb], 0, 0, 0);
        }
      }
    }
  }
  const size_t ob = (size_t)(mpow + jj) * 65536;
#pragma unroll
  for (int nb = 0; nb < 4; ++nb)
#pragma unroll
    for (int r = 0; r < 4; ++r) {
      const int row = m0 + w*16 + q*4 + r;
      const int col = n0 + nb*16 + ln;
      float v = acc[nb][r];
      unsigned short hi = f2u(v);
      Phi[ob + (size_t)row*256 + col] = hi;
      Plo[ob + (size_t)row*256 + col] = f2u(v - u2f(hi));
    }
}

// ---------------------------------------------------------------------------
// pack_all job (job = 0..3359), identical indexing to the old pack_all kernel:
//  job<2048:  Ghat[(j*256+e)][d] = P_{63-j}[d][e];  Q[e][(j*256+d)] = P_{j+1}[d][e]
//  else:      Qcat[2304][2048], G2[2048][256], LcT2hi/lo[e][d] = P2_8[d][e]
// ---------------------------------------------------------------------------
static __device__ void pack_all_job(int blk0, char* smem,
    const unsigned short* __restrict__ Phi,
    const unsigned short* __restrict__ Phi2, const unsigned short* __restrict__ Plo2,
    unsigned short* __restrict__ Ghat, unsigned short* __restrict__ Q,
    unsigned short* __restrict__ Qcat, unsigned short* __restrict__ G2,
    unsigned short* __restrict__ LcT2hi, unsigned short* __restrict__ LcT2lo)
{
  unsigned short (*tile)[65] = (unsigned short(*)[65])smem;
  const int tx = threadIdx.x & 63, ty = threadIdx.x >> 6;  // ty 0..3
  if (blk0 < 2048) {
    const int blk = blk0;
    int t16, jpar;
    const unsigned short* src;
    if (blk < 1024) { jpar = blk >> 4;            t16 = blk & 15;  src = Phi + (size_t)(63 - jpar) * 65536; }
    else            { int v = blk - 1024; jpar = v >> 4; t16 = v & 15; src = Phi + (size_t)(jpar + 1) * 65536; }
    const int d0 = (t16 & 3) * 64, e0 = (t16 >> 2) * 64;
#pragma unroll
    for (int s = 0; s < 16; ++s)
      tile[ty*16 + s][tx] = src[(size_t)(d0 + ty*16 + s) * 256 + e0 + tx];
    __syncthreads();
    if (blk < 1024) {
#pragma unroll
      for (int s = 0; s < 16; ++s) {
        const int e = e0 + ty*16 + s, d = d0 + tx;
        Ghat[((size_t)(jpar*256 + e)) * 256 + d] = tile[tx][ty*16 + s];
      }
    } else {
#pragma unroll
      for (int s = 0; s < 16; ++s) {
        const int e = e0 + ty*16 + s, d = d0 + tx;
        Q[(size_t)e * 16384 + jpar*256 + d] = tile[tx][ty*16 + s];
      }
    }
  } else {
    const int blk = blk0 - 2048;
    if (blk < 1152) {                                // Qcat: 36x32 tiles of 64x64
      const int rt = blk >> 5, ct = blk & 31;
      const int k0 = rt * 64, c0 = ct * 64;
      const int r = c0 >> 8, d0 = c0 & 255;
      int p = 0, e0 = 0;
      bool zero = false;
      if (k0 < 256) { p = r; e0 = k0; }
      else {
        const int u = (k0 - 256) >> 8; e0 = (k0 - 256) & 255;
        if (u >= r) zero = true; else p = r - 1 - u;
      }
      if (zero) {
#pragma unroll
        for (int s = 0; s < 16; ++s)
          Qcat[(size_t)(k0 + ty*16 + s) * 2048 + c0 + tx] = 0;
      } else {
        const unsigned short* src = Phi2 + (size_t)p * 65536;
#pragma unroll
        for (int s = 0; s < 16; ++s)
          tile[ty*16 + s][tx] = src[(size_t)(d0 + ty*16 + s) * 256 + e0 + tx];
        __syncthreads();
#pragma unroll
        for (int s = 0; s < 16; ++s)
          Qcat[(size_t)(k0 + ty*16 + s) * 2048 + c0 + tx] = tile[tx][ty*16 + s];
      }
    } else if (blk < 1280) {                         // G2: 32x4 tiles
      const int t = blk - 1152;
      const int rt = t >> 2, ct = t & 3;
      const int k0 = rt * 64, d0 = ct * 64;
      const int r = k0 >> 8, e0 = k0 & 255;
      const unsigned short* src = Phi2 + (size_t)(7 - r) * 65536;
#pragma unroll
      for (int s = 0; s < 16; ++s)
        tile[ty*16 + s][tx] = src[(size_t)(d0 + ty*16 + s) * 256 + e0 + tx];
      __syncthreads();
#pragma unroll
      for (int s = 0; s < 16; ++s)
        G2[(size_t)(k0 + ty*16 + s) * 256 + d0 + tx] = tile[tx][ty*16 + s];
    } else {                                         // LcT2 hi (16) + lo (16)
      const int t = blk - 1280;
      const int half = t >> 4, t16 = t & 15;
      const int d0 = (t16 & 3) * 64, e0 = (t16 >> 2) * 64;
      const unsigned short* src = (half ? Plo2 : Phi2) + (size_t)8 * 65536;
      unsigned short* dst = half ? LcT2lo : LcT2hi;
#pragma unroll
      for (int s = 0; s < 16; ++s)
        tile[ty*16 + s][tx] = src[(size_t)(d0 + ty*16 + s) * 256 + e0 + tx];
      __syncthreads();
#pragma unroll
      for (int s = 0; s < 16; ++s)
        dst[(size_t)(e0 + ty*16 + s) * 256 + d0 + tx] = tile[tx][ty*16 + s];
    }
  }
  __syncthreads();   // protect LDS tile reuse by the next job
}

// ---------------------------------------------------------------------------
// Chunk-summary GEMM job: S = Bx_r[1024,16384] @ Ghat[16384,256], split-K=8.
// job = 0..511: nz = job&3, my = (job>>2)&15, kz = job>>6.  Kper=2048.
// ---------------------------------------------------------------------------
static __device__ void sum_job(int job, char* smem,
    const unsigned short* __restrict__ Bx, const unsigned short* __restrict__ Ghat,
    float* __restrict__ Spart)
{
  unsigned short (*As)[72]  = (unsigned short(*)[72])smem;
  unsigned short (*Bst)[72] = (unsigned short(*)[72])(smem + 9216);
  const int tid = threadIdx.x, lane = tid & 63, w = tid >> 6;
  const int q = lane >> 4, ln = lane & 15;
  const long n0 = (long)(job & 3) * 64;
  const long m0 = (long)((job >> 2) & 15) * 64;
  const int  kz = job >> 6;
  const long kbase = (long)kz * 2048;
  const int sm = tid >> 2, sk = (tid & 3) << 4;
  v4f acc[4];
#pragma unroll
  for (int i = 0; i < 4; ++i) acc[i] = 0;

  for (int ks = 0; ks < 2048; ks += 64) {
    const long kg = kbase + ks;
    __syncthreads();
    {
      const unsigned short* A = Bx + (m0 + sm) * 16384L + kg + sk;
      v8s t0 = ((const v8s*)A)[0], t1 = ((const v8s*)A)[1];
      *(v8s*)&As[sm][sk] = t0; *(v8s*)&As[sm][sk + 8] = t1;
    }
    {
      const unsigned short* Bg = Ghat + (kg + sm) * 256L + n0 + sk;
      v8s b0 = ((const v8s*)Bg)[0], b1 = ((const v8s*)Bg)[1];
#pragma unroll
      for (int r = 0; r < 8; ++r) Bst[sk + r][sm] = (unsigned short)b0[r];
#pragma unroll
      for (int r = 0; r < 8; ++r) Bst[sk + 8 + r][sm] = (unsigned short)b1[r];
    }
    __syncthreads();
#pragma unroll
    for (int kb = 0; kb < 64; kb += 32) {
      v8s a = *(const v8s*)&As[w*16 + ln][kb + q*8];
#pragma unroll
      for (int nb = 0; nb < 4; ++nb) {
        v8s b = *(const v8s*)&Bst[nb*16 + ln][kb + q*8];
        acc[nb] = __builtin_amdgcn_mfma_f32_16x16x32_bf16(a, b, acc[nb], 0, 0, 0);
      }
    }
  }
#pragma unroll
  for (int nb = 0; nb < 4; ++nb)
#pragma unroll
    for (int r = 0; r < 4; ++r) {
      const long row = m0 + w*16 + q*4 + r;
      const long col = n0 + nb*16 + ln;
      Spart[(long)kz * 262144 + row * 256 + col] = acc[nb][r];
    }
}

// ---------------------------------------------------------------------------
// MEGA kernel (768 blocks x 256 threads, 3 blocks/CU, all co-resident):
//  blocks 0..255  : k5_scan (local scans, latency-chain bound, no barriers)
//  blocks 256..767: pow group — level-1 doubling (6 rounds) -> pack2 ->
//                   level-2 doubling (3 rounds) -> pack_all -> summary GEMM ->
//                   reduce_s2, with device-scope barriers between phases.
// launch_bounds(256,3): VGPR cap 168 (scan needs 148 — NO spills; R3's (256,2)
// cap of 128 spilled the bf[8][4] fragments and slowed the scan 6x).
// ---------------------------------------------------------------------------
__global__ __launch_bounds__(256, 3) void mega(
    const unsigned short* __restrict__ LamT, const unsigned short* __restrict__ Bx,
    float* __restrict__ Out,
    unsigned short* __restrict__ Phi,  unsigned short* __restrict__ Plo,
    unsigned short* __restrict__ Phi2, unsigned short* __restrict__ Plo2,
    unsigned short* __restrict__ Ghat, unsigned short* __restrict__ Q,
    unsigned short* __restrict__ Qcat, unsigned short* __restrict__ G2,
    unsigned short* __restrict__ LcT2hi, unsigned short* __restrict__ LcT2lo,
    float* __restrict__ Spart, unsigned short* __restrict__ Acat,
    unsigned int* __restrict__ cnt)
{
  __shared__ __align__(16) char smem[18432];   // max(scan 8448, pow 18432, pack 8320)
  const int tid = threadIdx.x;

  if (blockIdx.x < 256) {
    // ---------------- scan path (verbatim k5_scan) ----------------
    unsigned short (*gs)[264] = (unsigned short(*)[264])smem;
    const int lane = tid & 63, w = tid >> 6;  // 4 waves
    const int q = lane >> 4, ln = lane & 15;
    const int blk = blockIdx.x;
    const int b  = blk >> 4;            // batch
    const int i0 = (blk * 4) & 63;      // first chunk index of this block

    v8s bf[8][4];                        // Lam^T frags, cols [64w,64w+64)
#pragma unroll
    for (int kk = 0; kk < 8; ++kk)
#pragma unroll
      for (int nb = 0; nb < 4; ++nb) {
        const int n = 64*w + nb*16 + ln;
#pragma unroll
        for (int r = 0; r < 8; ++r)
          bf[kk][nb][r] = (short)LamT[(kk*32 + q*8 + r) * 256 + n];
      }
    for (int e = tid; e < 16*264; e += 256) (&gs[0][0])[e] = 0;

    size_t base[4];
#pragma unroll
    for (int r = 0; r < 4; ++r)
      base[r] = ((size_t)b*4096 + (size_t)(i0 + r)*64) * 256;   // row of step j=0
    const int colw = 64*w;

    unsigned short bxr[2][4][4];         // depth-2 Bx prefetch ring (q==0 lanes)
    if (q == 0) {
#pragma unroll
      for (int s = 0; s < 2; ++s)
#pragma unroll
        for (int r = 0; r < 4; ++r)
#pragma unroll
          for (int nb = 0; nb < 4; ++nb)
            bxr[s][r][nb] = Bx[base[r] + (size_t)s*256 + colw + nb*16 + ln];
    }
    lds_barrier();

#pragma unroll 2
    for (int j = 0; j < CHUNK; ++j) {
      v8s a[8];
#pragma unroll
      for (int kk = 0; kk < 8; ++kk) a[kk] = *(const v8s*)&gs[ln][kk*32 + q*8];
      lds_barrier();
      v4f acc[4];
#pragma unroll
      for (int nb = 0; nb < 4; ++nb) acc[nb] = 0;
#pragma unroll
      for (int kk = 0; kk < 8; ++kk)
#pragma unroll
        for (int nb = 0; nb < 4; ++nb)
          acc[nb] = __builtin_amdgcn_mfma_f32_16x16x32_bf16(a[kk], bf[kk][nb], acc[nb], 0, 0, 0);
      if (q == 0) {
#pragma unroll
        for (int r = 0; r < 4; ++r) {
          const size_t rb = base[r] + (size_t)j*256 + colw;
#pragma unroll
          for (int nb = 0; nb < 4; ++nb) {
            const float g = acc[nb][r] + u2f(bxr[j & 1][r][nb]);
            Out[rb + nb*16 + ln] = g;
            gs[r][colw + nb*16 + ln] = f2u(g);
          }
        }
        if (j < CHUNK - 2) {
#pragma unroll
          for (int r = 0; r < 4; ++r) {
            const size_t rb = base[r] + (size_t)(j + 2)*256 + colw;
#pragma unroll
            for (int nb = 0; nb < 4; ++nb)
              bxr[j & 1][r][nb] = Bx[rb + nb*16 + ln];
          }
        }
      }
      lds_barrier();
    }
    return;
  }

  // ---------------- pow group (512 blocks) ----------------
  const int pid = (int)blockIdx.x - 256;
  int bar = 0;
  // level-1 powers P_2..P_64 by doubling (6 rounds)
#pragma unroll 1
  for (int mp = 1; mp <= 32; mp <<= 1) {
    for (int job = pid; job < 16 * mp; job += NPB)
      pow_job(Phi, Plo, mp, job, smem);
    gbar(&cnt[bar++]);
  }
  // pack2: P2_0 = I, P2_1 = P_64 (hi/lo)  [sized for 256 blocks -> guard]
  if (pid < 256) {
    const int idx = pid * 256 + tid;
    const int dd = idx >> 8, ee = idx & 255;
    Phi2[idx] = (dd == ee) ? (unsigned short)0x3F80 : (unsigned short)0;
    Plo2[idx] = 0;
    Phi2[65536 + idx] = Phi[(size_t)64 * 65536 + idx];
    Plo2[65536 + idx] = Plo[(size_t)64 * 65536 + idx];
  }
  gbar(&cnt[bar++]);
  // level-2 powers P2_2..P2_8 (3 rounds)
#pragma unroll 1
  for (int mp = 1; mp <= 4; mp <<= 1) {
    for (int job = pid; job < 16 * mp; job += NPB)
      pow_job(Phi2, Plo2, mp, job, smem);
    gbar(&cnt[bar++]);
  }
  // pack all GEMM operands
  for (int job = pid; job < 3360; job += NPB)
    pack_all_job(job, smem, Phi, Phi2, Plo2, Ghat, Q, Qcat, G2, LcT2hi, LcT2lo);
  gbar(&cnt[bar++]);
  // chunk summaries: S = Bx_r[1024,16384] @ Ghat (split-K=8 -> Spart)
  for (int job = pid; job < 512; job += NPB)
    sum_job(job, smem, Bx, Ghat, Spart);
  gbar(&cnt[bar++]);
  // reduce split-K partials and scatter into Acat S-region
  for (int job = pid; job < 1024; job += NPB) {
    const int f = job * 256 + tid;
    float v = 0;
#pragma unroll
    for (int z = 0; z < 8; ++z) v += Spart[(size_t)z * 262144 + f];
    const int e = f & 255, i = (f >> 8) & 63, bb = f >> 14;
    const int u = i & 7, m = i >> 3;
    Acat[(size_t)(bb*8 + m) * 2304 + 256 + u*256 + e] = f2u(v);
  }
}

// ---------------------------------------------------------------------------
// Level-2 sequential combine: 8 steps, ONE workgroup, split-bf16 MFMA.
// A2_{b,m} (state entering superchunk m) written bf16 into Acat cols 0..255.
// ---------------------------------------------------------------------------
__global__ __launch_bounds__(512, 2) void k4b_combine(
    const unsigned short* __restrict__ LcT2hi, const unsigned short* __restrict__ LcT2lo,
    const float* __restrict__ S2, unsigned short* __restrict__ Acat)
{
  __shared__ unsigned short Hhi[16][264];
  __shared__ unsigned short Hlo[16][264];
  const int tid = threadIdx.x, lane = tid & 63, w = tid >> 6;  // 8 waves
  const int q = lane >> 4, ln = lane & 15;

  v8s bhi[8][2], blo[8][2];                       // (Lam^512)^T frags, cols [32w,32w+32)
#pragma unroll
  for (int kk = 0; kk < 8; ++kk)
#pragma unroll
    for (int nb = 0; nb < 2; ++nb) {
      const int n = 32*w + nb*16 + ln;
#pragma unroll
      for (int r = 0; r < 8; ++r) {
        const int k = kk*32 + q*8 + r;
        bhi[kk][nb][r] = (short)LcT2hi[k*256 + n];
        blo[kk][nb][r] = (short)LcT2lo[k*256 + n];
      }
    }
  for (int e = tid; e < 16*264; e += 512) { (&Hhi[0][0])[e] = 0; (&Hlo[0][0])[e] = 0; }
  lds_barrier();

  for (int m = 0; m < 8; ++m) {
    // A2_{b,m} = state BEFORE absorbing superchunk m
    for (int e = tid; e < 4096; e += 512) {
      const int b = e >> 8, d = e & 255;
      Acat[(size_t)(b*8 + m) * 2304 + d] = Hhi[b][d];
    }
    v8s ahi[8], alo[8];
#pragma unroll
    for (int kk = 0; kk < 8; ++kk) {
      ahi[kk] = *(const v8s*)&Hhi[ln][kk*32 + q*8];
      alo[kk] = *(const v8s*)&Hlo[ln][kk*32 + q*8];
    }
    lds_barrier();
    v4f acc[2];
#pragma unroll
    for (int nb = 0; nb < 2; ++nb)
#pragma unroll
      for (int r = 0; r < 4; ++r) {
        const int bb = 4*q + r, col = 32*w + nb*16 + ln;
        acc[nb][r] = S2[(size_t)(bb*8 + m) * 256 + col];
      }
#pragma unroll
    for (int kk = 0; kk < 8; ++kk)
#pragma unroll
      for (int nb = 0; nb < 2; ++nb) {
        acc[nb] = __builtin_amdgcn_mfma_f32_16x16x32_bf16(ahi[kk], bhi[kk][nb], acc[nb], 0, 0, 0);
        acc[nb] = __builtin_amdgcn_mfma_f32_16x16x32_bf16(alo[kk], bhi[kk][nb], acc[nb], 0, 0, 0);
        acc[nb] = __builtin_amdgcn_mfma_f32_16x16x32_bf16(ahi[kk], blo[kk][nb], acc[nb], 0, 0, 0);
      }
#pragma unroll
    for (int nb = 0; nb < 2; ++nb)
#pragma unroll
      for (int r = 0; r < 4; ++r) {
        const int bb = 4*q + r, col = 32*w + nb*16 + ln;
        float v = acc[nb][r];
        unsigned short hi = f2u(v);
        Hhi[bb][col] = hi;
        Hlo[bb][col] = f2u(v - u2f(hi));
      }
    lds_barrier();
  }
}

// ---------------------------------------------------------------------------
extern "C" void kernel_launch(void* const* d_in, const int* in_sizes, int n_in,
                              void* d_out, int out_size, void* d_ws, size_t ws_size,
                              hipStream_t stream)
{
  const float* x   = (const float*)d_in[0];
  const float* Bm  = (const float*)d_in[1];
  const float* Lam = (const float*)d_in[2];
  float* Out = (float*)d_out;
  (void)in_sizes; (void)n_in; (void)out_size; (void)ws_size;

  char* ws = (char*)d_ws;
  size_t off = 0;
  auto alloc = [&](size_t bytes) { void* p = ws + off; off += (bytes + 255) & ~(size_t)255; return p; };
  unsigned short* Bx    = (unsigned short*)alloc((size_t)16777216 * 2);      // 32 MB
  unsigned short* Phi   = (unsigned short*)alloc((size_t)65 * 65536 * 2);    // 8.3 MB
  unsigned short* Plo   = (unsigned short*)alloc((size_t)65 * 65536 * 2);    // 8.3 MB
  unsigned short* Ghat  = (unsigned short*)alloc((size_t)16384 * 256 * 2);   // 8 MB
  unsigned short* Q     = (unsigned short*)alloc((size_t)256 * 16384 * 2);   // 8 MB
  unsigned short* Qcat  = (unsigned short*)alloc((size_t)2304 * 2048 * 2);   // 9.4 MB
  unsigned short* G2    = (unsigned short*)alloc((size_t)2048 * 256 * 2);    // 1 MB
  unsigned short* Phi2  = (unsigned short*)alloc((size_t)9 * 65536 * 2);
  unsigned short* Plo2  = (unsigned short*)alloc((size_t)9 * 65536 * 2);
  unsigned short* Bt    = (unsigned short*)alloc(131072);
  unsigned short* LamT  = (unsigned short*)alloc(131072);
  unsigned short* LcT2hi= (unsigned short*)alloc(131072);
  unsigned short* LcT2lo= (unsigned short*)alloc(131072);
  unsigned short* Acat  = (unsigned short*)alloc((size_t)128 * 2304 * 2);    // 0.6 MB
  float*          S2    = (float*)alloc(131072);
  unsigned short* Abf   = (unsigned short*)alloc(524288);
  unsigned int*   cnt   = (unsigned int*)alloc(256);                         // barrier counters
  float*          Spart = (float*)Plo;  // alias: Plo dead before summary phase writes Spart

  // 1) packs + P0/P1 (+ zero mega barrier counters — replay-safe)
  pack_init<<<dim3(256), dim3(256), 0, stream>>>(Bm, Lam, Bt, LamT, Phi, Plo, cnt);
  // 2) Bx = x @ B^T  (bf16 out)
  gemm_tile<true, true, false><<<dim3(4, 1024, 1), dim3(256), 0, stream>>>(
      (const void*)x, Bt, (void*)Bx, 256, 256, 256, 256, 0);
  // 3) MEGA: local scans (blocks 0..255) || power/pack/summary chain (256..767)
  mega<<<dim3(768), dim3(256), 0, stream>>>(LamT, Bx, Out,
      Phi, Plo, Phi2, Plo2, Ghat, Q, Qcat, G2, LcT2hi, LcT2lo, Spart, Acat, cnt);
  // 4) level-2 summaries: S2[128,256] = Acat_S[128,2048] @ G2
  gemm_tile<false, false, false><<<dim3(4, 2, 1), dim3(256), 0, stream>>>(
      (const void*)(Acat + 256), G2, (void*)S2, 2304, 256, 256, 2048, 0);
  // 5) sequential combine over 8 superchunks -> A2 into Acat cols 0..255
  k4b_combine<<<dim3(1), dim3(512), 0, stream>>>(LcT2hi, LcT2lo, S2, Acat);
  // 6) all chunk-entry states in one GEMM: Abf[128,2048] = Acat[128,2304] @ Qcat
  gemm_tile<false, true, false><<<dim3(32, 2, 1), dim3(256), 0, stream>>>(
      (const void*)Acat, Qcat, (void*)Abf, 2304, 2048, 2048, 2304, 0);
  // 7) carry GEMM with += epilogue: Out = Abf @ Q + Out(g_local)
  gemm_tile<false, false, true><<<dim3(256, 16, 1), dim3(256), 0, stream>>>(
      (const void*)Abf, Q, (void*)Out, 256, 16384, 16384, 256, 0);
}

// Round 3
// 883.005 us; speedup vs baseline: 1.6839x; 1.6839x over previous
//
#include <hip/hip_runtime.h>
#include <hip/hip_bf16.h>
#include <stdint.h>

// Problem: h_t = Lam @ h_{t-1} + B @ x_t ; BS=16, T=4096, D=256, fp32 in/out.
// Two-level chunked scan: level-1 chunks c=64, level-2 superchunks of 8.
// R5: NO VGPR cap on mega. R3 (256,2)=128cap and R4 (256,3)=~168-split both
// wrecked the scan's persistent bf[8][4] Lam fragments (needs 148 natural
// VGPRs; measured 67us standalone). Plain launch_bounds(256): compiler
// allocates ~148 -> 3 blocks/CU natural occupancy. Pow group back to 256
// blocks (grid 512) so co-residency for gbar holds even at 2 blocks/CU.

#define CHUNK 64
#define NPB   256   // pow-group block count

typedef short v8s __attribute__((ext_vector_type(8)));   // 8 x bf16 (4 VGPRs)
typedef float v4f __attribute__((ext_vector_type(4)));   // MFMA accum

static __device__ __forceinline__ unsigned short f2u(float f) {
  union { float f; unsigned int u; } x; x.f = f;
  unsigned int u = x.u + 0x7FFFu + ((x.u >> 16) & 1u);   // RNE f32->bf16
  return (unsigned short)(u >> 16);
}
static __device__ __forceinline__ float u2f(unsigned short h) {
  union { unsigned int u; float f; } x; x.u = ((unsigned int)h) << 16;
  return x.f;
}
// Workgroup barrier that only drains LDS (lgkmcnt), leaving vmcnt free-running
// so register prefetch loads survive across it.
static __device__ __forceinline__ void lds_barrier() {
  asm volatile("s_waitcnt lgkmcnt(0)\n\ts_barrier" ::: "memory");
}
// Device-scope barrier among the NPB pow-group blocks. One counter per phase
// (no reset during the kernel -> no reset race); counters are zeroed by
// pack_init at the head of every launch/replay. All threads fence (release)
// before arrival; thread 0 fences (acquire) after the spin.
static __device__ __forceinline__ void gbar(unsigned* c) {
  __threadfence();
  __syncthreads();
  if (threadIdx.x == 0) {
    atomicAdd(c, 1u);
    while (__hip_atomic_load(c, __ATOMIC_RELAXED, __HIP_MEMORY_SCOPE_AGENT) < NPB)
      __builtin_amdgcn_s_sleep(2);
    __threadfence();
  }
  __syncthreads();
}

// ---------------------------------------------------------------------------
// Generic 64x64-tile bf16 MFMA GEMM. A: f32 or bf16 row-major [M,K] (lda).
// B: bf16 row-major [K,N] (ldb). C: f32 or bf16 [M,N] (ldc).
// blockIdx = (n_tile, m_tile, k_split). Per-split K length = Kper.
// Split partials go to C + z*csplit (f32 path only). ADD_C: C += A*B (f32).
// ---------------------------------------------------------------------------
template<bool A_F32, bool C_BF16, bool ADD_C>
__global__ __launch_bounds__(256) void gemm_tile(
    const void* __restrict__ Ap, const unsigned short* __restrict__ Bp,
    void* __restrict__ Cp, int lda, int ldb, int ldc, int Kper, long csplit)
{
  __shared__ unsigned short As[64][72];   // [m][k], pad to kill bank conflicts
  __shared__ unsigned short Bst[64][72];  // [n][k] (transposed for b128 frag reads)
  const int tid = threadIdx.x;
  const int lane = tid & 63, w = tid >> 6;       // 4 waves
  const int q = lane >> 4, ln = lane & 15;
  const long n0 = (long)blockIdx.x * 64;
  const long m0 = (long)blockIdx.y * 64;
  const int  kz = blockIdx.z;
  const long kbase = (long)kz * Kper;
  const int sm = tid >> 2;          // staging row 0..63
  const int sk = (tid & 3) << 4;    // staging col 0,16,32,48

  v4f acc[4];
#pragma unroll
  for (int i = 0; i < 4; ++i) acc[i] = 0;

  for (int ks = 0; ks < Kper; ks += 64) {
    const long kg = kbase + ks;
    __syncthreads();
    if (A_F32) {
      const float* A = (const float*)Ap + (m0 + sm) * (long)lda + kg + sk;
      float4 f[4];
#pragma unroll
      for (int t = 0; t < 4; ++t) f[t] = ((const float4*)A)[t];
      unsigned short* d = &As[sm][sk];
#pragma unroll
      for (int t = 0; t < 4; ++t) {
        d[4*t+0] = f2u(f[t].x); d[4*t+1] = f2u(f[t].y);
        d[4*t+2] = f2u(f[t].z); d[4*t+3] = f2u(f[t].w);
      }
    } else {
      const unsigned short* A = (const unsigned short*)Ap + (m0 + sm) * (long)lda + kg + sk;
      v8s t0 = ((const v8s*)A)[0], t1 = ((const v8s*)A)[1];
      *(v8s*)&As[sm][sk] = t0; *(v8s*)&As[sm][sk + 8] = t1;
    }
    // stage B (transpose into [n][k])
    {
      const unsigned short* Bg = Bp + (kg + sm) * (long)ldb + n0 + sk;
      v8s b0 = ((const v8s*)Bg)[0], b1 = ((const v8s*)Bg)[1];
#pragma unroll
      for (int r = 0; r < 8; ++r) Bst[sk + r][sm] = (unsigned short)b0[r];
#pragma unroll
      for (int r = 0; r < 8; ++r) Bst[sk + 8 + r][sm] = (unsigned short)b1[r];
    }
    __syncthreads();
#pragma unroll
    for (int kb = 0; kb < 64; kb += 32) {
      v8s a = *(const v8s*)&As[w*16 + ln][kb + q*8];
#pragma unroll
      for (int nb = 0; nb < 4; ++nb) {
        v8s b = *(const v8s*)&Bst[nb*16 + ln][kb + q*8];
        acc[nb] = __builtin_amdgcn_mfma_f32_16x16x32_bf16(a, b, acc[nb], 0, 0, 0);
      }
    }
  }
#pragma unroll
  for (int nb = 0; nb < 4; ++nb)
#pragma unroll
    for (int r = 0; r < 4; ++r) {
      const long row = m0 + w*16 + q*4 + r;        // D row = 4q+r within wave's 16
      const long col = n0 + nb*16 + ln;
      float v = acc[nb][r];
      if (C_BF16) ((unsigned short*)Cp)[row * (long)ldc + col] = f2u(v);
      else {
        float* Cf = (float*)Cp + (long)kz * csplit;
        if (ADD_C) v += Cf[row * (long)ldc + col];
        Cf[row * (long)ldc + col] = v;
      }
    }
}

// ---------------------------------------------------------------------------
// pack_init: Bt[e][d]=B[d][e], LamT[e][d]=Lam[d][e] (bf16); P_0=I, P_1=Lam hi/lo.
// Also zeroes the mega-kernel barrier counters (replay-safe).
// ---------------------------------------------------------------------------
__global__ __launch_bounds__(256) void pack_init(
    const float* __restrict__ Bm, const float* __restrict__ Lam,
    unsigned short* __restrict__ Bt, unsigned short* __restrict__ LamT,
    unsigned short* __restrict__ Phi, unsigned short* __restrict__ Plo,
    unsigned int* __restrict__ cnt)
{
  if (blockIdx.x == 0 && threadIdx.x < 16) cnt[threadIdx.x] = 0;
  const int idx = blockIdx.x * 256 + threadIdx.x;  // 0..65535
  const int e = idx >> 8, d = idx & 255;
  Bt[idx]   = f2u(Bm[d * 256 + e]);
  LamT[idx] = f2u(Lam[d * 256 + e]);
  float v = Lam[idx];                              // idx as (dd,ee) row-major
  unsigned short hi = f2u(v);
  Phi[65536 + idx] = hi;
  Plo[65536 + idx] = f2u(v - u2f(hi));
  const int dd = idx >> 8, ee = idx & 255;
  Phi[idx] = (dd == ee) ? (unsigned short)0x3F80 : (unsigned short)0;
  Plo[idx] = 0;
}

// ---------------------------------------------------------------------------
// Pow-job: P_{mpow+jj} = P_mpow * P_jj, split-bf16 (hi+lo):
// acc = Ah*Bh + Al*Bh + Ah*Bl (drops lo*lo) -> ~fp32. One 64x64 output tile.
// job encodes (jj, n0, m0); jobs per round = 16*mpow.
// ---------------------------------------------------------------------------
static __device__ void pow_job(unsigned short* __restrict__ Phi,
                               unsigned short* __restrict__ Plo,
                               int mpow, int job, char* smem)
{
  unsigned short (*As)[72]  = (unsigned short(*)[72])smem;
  unsigned short (*Bst)[72] = (unsigned short(*)[72])(smem + 9216);
  const int tid = threadIdx.x, lane = tid & 63, w = tid >> 6;
  const int q = lane >> 4, ln = lane & 15;
  const int jj = (job >> 4) + 1;
  const int n0 = (job & 3) * 64;
  const int m0 = ((job >> 2) & 3) * 64;
  const unsigned short* Ah = Phi + (size_t)mpow * 65536;
  const unsigned short* Al = Plo + (size_t)mpow * 65536;
  const unsigned short* Bh = Phi + (size_t)jj * 65536;
  const unsigned short* Bl = Plo + (size_t)jj * 65536;
  const int sm = tid >> 2, sk = (tid & 3) << 4;
  v4f acc[4];
#pragma unroll
  for (int i = 0; i < 4; ++i) acc[i] = 0;

  for (int seg = 0; seg < 3; ++seg) {
    const unsigned short* Asrc = (seg == 1) ? Al : Ah;
    const unsigned short* Bsrc = (seg == 2) ? Bl : Bh;
    for (int ks = 0; ks < 256; ks += 64) {
      __syncthreads();
      {
        const unsigned short* Ag = Asrc + (size_t)(m0 + sm) * 256 + ks + sk;
        v8s t0 = ((const v8s*)Ag)[0], t1 = ((const v8s*)Ag)[1];
        *(v8s*)&As[sm][sk] = t0; *(v8s*)&As[sm][sk + 8] = t1;
      }
      {
        const unsigned short* Bg = Bsrc + (size_t)(ks + sm) * 256 + n0 + sk;
        v8s b0 = ((const v8s*)Bg)[0], b1 = ((const v8s*)Bg)[1];
#pragma unroll
        for (int r = 0; r < 8; ++r) Bst[sk + r][sm] = (unsigned short)b0[r];
#pragma unroll
        for (int r = 0; r < 8; ++r) Bst[sk + 8 + r][sm] = (unsigned short)b1[r];
      }
      __syncthreads();
#pragma unroll
      for (int kb = 0; kb < 64; kb += 32) {
        v8s a = *(const v8s*)&As[w*16 + ln][kb + q*8];
#pragma unroll
        for (int nb = 0; nb < 4; ++nb) {
          v8s bb = *(const v8s*)&Bst[nb*16 + ln][kb + q*8];
          acc[nb] = __builtin_amdgcn_mfma_f32_16x16x32_bf16(a, bb, acc[nb], 0, 0, 0);
        }
      }
    }
  }
  const size_t ob = (size_t)(mpow + jj) * 65536;
#pragma unroll
  for (int nb = 0; nb < 4; ++nb)
#pragma unroll
    for (int r = 0; r < 4; ++r) {
      const int row = m0 + w*16 + q*4 + r;
      const int col = n0 + nb*16 + ln;
      float v = acc[nb][r];
      unsigned short hi = f2u(v);
      Phi[ob + (size_t)row*256 + col] = hi;
      Plo[ob + (size_t)row*256 + col] = f2u(v - u2f(hi));
    }
}

// ---------------------------------------------------------------------------
// pack_all job (job = 0..3359), identical indexing to the old pack_all kernel:
//  job<2048:  Ghat[(j*256+e)][d] = P_{63-j}[d][e];  Q[e][(j*256+d)] = P_{j+1}[d][e]
//  else:      Qcat[2304][2048], G2[2048][256], LcT2hi/lo[e][d] = P2_8[d][e]
// ---------------------------------------------------------------------------
static __device__ void pack_all_job(int blk0, char* smem,
    const unsigned short* __restrict__ Phi,
    const unsigned short* __restrict__ Phi2, const unsigned short* __restrict__ Plo2,
    unsigned short* __restrict__ Ghat, unsigned short* __restrict__ Q,
    unsigned short* __restrict__ Qcat, unsigned short* __restrict__ G2,
    unsigned short* __restrict__ LcT2hi, unsigned short* __restrict__ LcT2lo)
{
  unsigned short (*tile)[65] = (unsigned short(*)[65])smem;
  const int tx = threadIdx.x & 63, ty = threadIdx.x >> 6;  // ty 0..3
  if (blk0 < 2048) {
    const int blk = blk0;
    int t16, jpar;
    const unsigned short* src;
    if (blk < 1024) { jpar = blk >> 4;            t16 = blk & 15;  src = Phi + (size_t)(63 - jpar) * 65536; }
    else            { int v = blk - 1024; jpar = v >> 4; t16 = v & 15; src = Phi + (size_t)(jpar + 1) * 65536; }
    const int d0 = (t16 & 3) * 64, e0 = (t16 >> 2) * 64;
#pragma unroll
    for (int s = 0; s < 16; ++s)
      tile[ty*16 + s][tx] = src[(size_t)(d0 + ty*16 + s) * 256 + e0 + tx];
    __syncthreads();
    if (blk < 1024) {
#pragma unroll
      for (int s = 0; s < 16; ++s) {
        const int e = e0 + ty*16 + s, d = d0 + tx;
        Ghat[((size_t)(jpar*256 + e)) * 256 + d] = tile[tx][ty*16 + s];
      }
    } else {
#pragma unroll
      for (int s = 0; s < 16; ++s) {
        const int e = e0 + ty*16 + s, d = d0 + tx;
        Q[(size_t)e * 16384 + jpar*256 + d] = tile[tx][ty*16 + s];
      }
    }
  } else {
    const int blk = blk0 - 2048;
    if (blk < 1152) {                                // Qcat: 36x32 tiles of 64x64
      const int rt = blk >> 5, ct = blk & 31;
      const int k0 = rt * 64, c0 = ct * 64;
      const int r = c0 >> 8, d0 = c0 & 255;
      int p = 0, e0 = 0;
      bool zero = false;
      if (k0 < 256) { p = r; e0 = k0; }
      else {
        const int u = (k0 - 256) >> 8; e0 = (k0 - 256) & 255;
        if (u >= r) zero = true; else p = r - 1 - u;
      }
      if (zero) {
#pragma unroll
        for (int s = 0; s < 16; ++s)
          Qcat[(size_t)(k0 + ty*16 + s) * 2048 + c0 + tx] = 0;
      } else {
        const unsigned short* src = Phi2 + (size_t)p * 65536;
#pragma unroll
        for (int s = 0; s < 16; ++s)
          tile[ty*16 + s][tx] = src[(size_t)(d0 + ty*16 + s) * 256 + e0 + tx];
        __syncthreads();
#pragma unroll
        for (int s = 0; s < 16; ++s)
          Qcat[(size_t)(k0 + ty*16 + s) * 2048 + c0 + tx] = tile[tx][ty*16 + s];
      }
    } else if (blk < 1280) {                         // G2: 32x4 tiles
      const int t = blk - 1152;
      const int rt = t >> 2, ct = t & 3;
      const int k0 = rt * 64, d0 = ct * 64;
      const int r = k0 >> 8, e0 = k0 & 255;
      const unsigned short* src = Phi2 + (size_t)(7 - r) * 65536;
#pragma unroll
      for (int s = 0; s < 16; ++s)
        tile[ty*16 + s][tx] = src[(size_t)(d0 + ty*16 + s) * 256 + e0 + tx];
      __syncthreads();
#pragma unroll
      for (int s = 0; s < 16; ++s)
        G2[(size_t)(k0 + ty*16 + s) * 256 + d0 + tx] = tile[tx][ty*16 + s];
    } else {                                         // LcT2 hi (16) + lo (16)
      const int t = blk - 1280;
      const int half = t >> 4, t16 = t & 15;
      const int d0 = (t16 & 3) * 64, e0 = (t16 >> 2) * 64;
      const unsigned short* src = (half ? Plo2 : Phi2) + (size_t)8 * 65536;
      unsigned short* dst = half ? LcT2lo : LcT2hi;
#pragma unroll
      for (int s = 0; s < 16; ++s)
        tile[ty*16 + s][tx] = src[(size_t)(d0 + ty*16 + s) * 256 + e0 + tx];
      __syncthreads();
#pragma unroll
      for (int s = 0; s < 16; ++s)
        dst[(size_t)(e0 + ty*16 + s) * 256 + d0 + tx] = tile[tx][ty*16 + s];
    }
  }
  __syncthreads();   // protect LDS tile reuse by the next job
}

// ---------------------------------------------------------------------------
// Chunk-summary GEMM job: S = Bx_r[1024,16384] @ Ghat[16384,256], split-K=8.
// job = 0..511: nz = job&3, my = (job>>2)&15, kz = job>>6.  Kper=2048.
// ---------------------------------------------------------------------------
static __device__ void sum_job(int job, char* smem,
    const unsigned short* __restrict__ Bx, const unsigned short* __restrict__ Ghat,
    float* __restrict__ Spart)
{
  unsigned short (*As)[72]  = (unsigned short(*)[72])smem;
  unsigned short (*Bst)[72] = (unsigned short(*)[72])(smem + 9216);
  const int tid = threadIdx.x, lane = tid & 63, w = tid >> 6;
  const int q = lane >> 4, ln = lane & 15;
  const long n0 = (long)(job & 3) * 64;
  const long m0 = (long)((job >> 2) & 15) * 64;
  const int  kz = job >> 6;
  const long kbase = (long)kz * 2048;
  const int sm = tid >> 2, sk = (tid & 3) << 4;
  v4f acc[4];
#pragma unroll
  for (int i = 0; i < 4; ++i) acc[i] = 0;

  for (int ks = 0; ks < 2048; ks += 64) {
    const long kg = kbase + ks;
    __syncthreads();
    {
      const unsigned short* A = Bx + (m0 + sm) * 16384L + kg + sk;
      v8s t0 = ((const v8s*)A)[0], t1 = ((const v8s*)A)[1];
      *(v8s*)&As[sm][sk] = t0; *(v8s*)&As[sm][sk + 8] = t1;
    }
    {
      const unsigned short* Bg = Ghat + (kg + sm) * 256L + n0 + sk;
      v8s b0 = ((const v8s*)Bg)[0], b1 = ((const v8s*)Bg)[1];
#pragma unroll
      for (int r = 0; r < 8; ++r) Bst[sk + r][sm] = (unsigned short)b0[r];
#pragma unroll
      for (int r = 0; r < 8; ++r) Bst[sk + 8 + r][sm] = (unsigned short)b1[r];
    }
    __syncthreads();
#pragma unroll
    for (int kb = 0; kb < 64; kb += 32) {
      v8s a = *(const v8s*)&As[w*16 + ln][kb + q*8];
#pragma unroll
      for (int nb = 0; nb < 4; ++nb) {
        v8s b = *(const v8s*)&Bst[nb*16 + ln][kb + q*8];
        acc[nb] = __builtin_amdgcn_mfma_f32_16x16x32_bf16(a, b, acc[nb], 0, 0, 0);
      }
    }
  }
#pragma unroll
  for (int nb = 0; nb < 4; ++nb)
#pragma unroll
    for (int r = 0; r < 4; ++r) {
      const long row = m0 + w*16 + q*4 + r;
      const long col = n0 + nb*16 + ln;
      Spart[(long)kz * 262144 + row * 256 + col] = acc[nb][r];
    }
}

// ---------------------------------------------------------------------------
// MEGA kernel (512 blocks x 256 threads; NO VGPR cap — scan path needs ~148):
//  blocks 0..255  : k5_scan (local scans, latency-chain bound, no barriers)
//  blocks 256..511: pow group — level-1 doubling (6 rounds) -> pack2 ->
//                   level-2 doubling (3 rounds) -> pack_all -> summary GEMM ->
//                   reduce_s2, with device-scope barriers between phases.
// Co-residency: 512 blocks fit at 2 blocks/CU (holds for any VGPR<=256).
// ---------------------------------------------------------------------------
__global__ __launch_bounds__(256) void mega(
    const unsigned short* __restrict__ LamT, const unsigned short* __restrict__ Bx,
    float* __restrict__ Out,
    unsigned short* __restrict__ Phi,  unsigned short* __restrict__ Plo,
    unsigned short* __restrict__ Phi2, unsigned short* __restrict__ Plo2,
    unsigned short* __restrict__ Ghat, unsigned short* __restrict__ Q,
    unsigned short* __restrict__ Qcat, unsigned short* __restrict__ G2,
    unsigned short* __restrict__ LcT2hi, unsigned short* __restrict__ LcT2lo,
    float* __restrict__ Spart, unsigned short* __restrict__ Acat,
    unsigned int* __restrict__ cnt)
{
  __shared__ __align__(16) char smem[18432];   // max(scan 8448, pow 18432, pack 8320)
  const int tid = threadIdx.x;

  if (blockIdx.x < 256) {
    // ---------------- scan path (verbatim k5_scan) ----------------
    unsigned short (*gs)[264] = (unsigned short(*)[264])smem;
    const int lane = tid & 63, w = tid >> 6;  // 4 waves
    const int q = lane >> 4, ln = lane & 15;
    const int blk = blockIdx.x;
    const int b  = blk >> 4;            // batch
    const int i0 = (blk * 4) & 63;      // first chunk index of this block

    v8s bf[8][4];                        // Lam^T frags, cols [64w,64w+64)
#pragma unroll
    for (int kk = 0; kk < 8; ++kk)
#pragma unroll
      for (int nb = 0; nb < 4; ++nb) {
        const int n = 64*w + nb*16 + ln;
#pragma unroll
        for (int r = 0; r < 8; ++r)
          bf[kk][nb][r] = (short)LamT[(kk*32 + q*8 + r) * 256 + n];
      }
    for (int e = tid; e < 16*264; e += 256) (&gs[0][0])[e] = 0;

    size_t base[4];
#pragma unroll
    for (int r = 0; r < 4; ++r)
      base[r] = ((size_t)b*4096 + (size_t)(i0 + r)*64) * 256;   // row of step j=0
    const int colw = 64*w;

    unsigned short bxr[2][4][4];         // depth-2 Bx prefetch ring (q==0 lanes)
    if (q == 0) {
#pragma unroll
      for (int s = 0; s < 2; ++s)
#pragma unroll
        for (int r = 0; r < 4; ++r)
#pragma unroll
          for (int nb = 0; nb < 4; ++nb)
            bxr[s][r][nb] = Bx[base[r] + (size_t)s*256 + colw + nb*16 + ln];
    }
    lds_barrier();

#pragma unroll 2
    for (int j = 0; j < CHUNK; ++j) {
      v8s a[8];
#pragma unroll
      for (int kk = 0; kk < 8; ++kk) a[kk] = *(const v8s*)&gs[ln][kk*32 + q*8];
      lds_barrier();
      v4f acc[4];
#pragma unroll
      for (int nb = 0; nb < 4; ++nb) acc[nb] = 0;
#pragma unroll
      for (int kk = 0; kk < 8; ++kk)
#pragma unroll
        for (int nb = 0; nb < 4; ++nb)
          acc[nb] = __builtin_amdgcn_mfma_f32_16x16x32_bf16(a[kk], bf[kk][nb], acc[nb], 0, 0, 0);
      if (q == 0) {
#pragma unroll
        for (int r = 0; r < 4; ++r) {
          const size_t rb = base[r] + (size_t)j*256 + colw;
#pragma unroll
          for (int nb = 0; nb < 4; ++nb) {
            const float g = acc[nb][r] + u2f(bxr[j & 1][r][nb]);
            Out[rb + nb*16 + ln] = g;
            gs[r][colw + nb*16 + ln] = f2u(g);
          }
        }
        if (j < CHUNK - 2) {
#pragma unroll
          for (int r = 0; r < 4; ++r) {
            const size_t rb = base[r] + (size_t)(j + 2)*256 + colw;
#pragma unroll
            for (int nb = 0; nb < 4; ++nb)
              bxr[j & 1][r][nb] = Bx[rb + nb*16 + ln];
          }
        }
      }
      lds_barrier();
    }
    return;
  }

  // ---------------- pow group (256 blocks) ----------------
  const int pid = (int)blockIdx.x - 256;
  int bar = 0;
  // level-1 powers P_2..P_64 by doubling (6 rounds)
#pragma unroll 1
  for (int mp = 1; mp <= 32; mp <<= 1) {
    for (int job = pid; job < 16 * mp; job += NPB)
      pow_job(Phi, Plo, mp, job, smem);
    gbar(&cnt[bar++]);
  }
  // pack2: P2_0 = I, P2_1 = P_64 (hi/lo)
  {
    const int idx = pid * 256 + tid;
    const int dd = idx >> 8, ee = idx & 255;
    Phi2[idx] = (dd == ee) ? (unsigned short)0x3F80 : (unsigned short)0;
    Plo2[idx] = 0;
    Phi2[65536 + idx] = Phi[(size_t)64 * 65536 + idx];
    Plo2[65536 + idx] = Plo[(size_t)64 * 65536 + idx];
  }
  gbar(&cnt[bar++]);
  // level-2 powers P2_2..P2_8 (3 rounds)
#pragma unroll 1
  for (int mp = 1; mp <= 4; mp <<= 1) {
    for (int job = pid; job < 16 * mp; job += NPB)
      pow_job(Phi2, Plo2, mp, job, smem);
    gbar(&cnt[bar++]);
  }
  // pack all GEMM operands
  for (int job = pid; job < 3360; job += NPB)
    pack_all_job(job, smem, Phi, Phi2, Plo2, Ghat, Q, Qcat, G2, LcT2hi, LcT2lo);
  gbar(&cnt[bar++]);
  // chunk summaries: S = Bx_r[1024,16384] @ Ghat (split-K=8 -> Spart)
  for (int job = pid; job < 512; job += NPB)
    sum_job(job, smem, Bx, Ghat, Spart);
  gbar(&cnt[bar++]);
  // reduce split-K partials and scatter into Acat S-region
  for (int job = pid; job < 1024; job += NPB) {
    const int f = job * 256 + tid;
    float v = 0;
#pragma unroll
    for (int z = 0; z < 8; ++z) v += Spart[(size_t)z * 262144 + f];
    const int e = f & 255, i = (f >> 8) & 63, bb = f >> 14;
    const int u = i & 7, m = i >> 3;
    Acat[(size_t)(bb*8 + m) * 2304 + 256 + u*256 + e] = f2u(v);
  }
}

// ---------------------------------------------------------------------------
// Level-2 sequential combine: 8 steps, ONE workgroup, split-bf16 MFMA.
// A2_{b,m} (state entering superchunk m) written bf16 into Acat cols 0..255.
// ---------------------------------------------------------------------------
__global__ __launch_bounds__(512, 2) void k4b_combine(
    const unsigned short* __restrict__ LcT2hi, const unsigned short* __restrict__ LcT2lo,
    const float* __restrict__ S2, unsigned short* __restrict__ Acat)
{
  __shared__ unsigned short Hhi[16][264];
  __shared__ unsigned short Hlo[16][264];
  const int tid = threadIdx.x, lane = tid & 63, w = tid >> 6;  // 8 waves
  const int q = lane >> 4, ln = lane & 15;

  v8s bhi[8][2], blo[8][2];                       // (Lam^512)^T frags, cols [32w,32w+32)
#pragma unroll
  for (int kk = 0; kk < 8; ++kk)
#pragma unroll
    for (int nb = 0; nb < 2; ++nb) {
      const int n = 32*w + nb*16 + ln;
#pragma unroll
      for (int r = 0; r < 8; ++r) {
        const int k = kk*32 + q*8 + r;
        bhi[kk][nb][r] = (short)LcT2hi[k*256 + n];
        blo[kk][nb][r] = (short)LcT2lo[k*256 + n];
      }
    }
  for (int e = tid; e < 16*264; e += 512) { (&Hhi[0][0])[e] = 0; (&Hlo[0][0])[e] = 0; }
  lds_barrier();

  for (int m = 0; m < 8; ++m) {
    // A2_{b,m} = state BEFORE absorbing superchunk m
    for (int e = tid; e < 4096; e += 512) {
      const int b = e >> 8, d = e & 255;
      Acat[(size_t)(b*8 + m) * 2304 + d] = Hhi[b][d];
    }
    v8s ahi[8], alo[8];
#pragma unroll
    for (int kk = 0; kk < 8; ++kk) {
      ahi[kk] = *(const v8s*)&Hhi[ln][kk*32 + q*8];
      alo[kk] = *(const v8s*)&Hlo[ln][kk*32 + q*8];
    }
    lds_barrier();
    v4f acc[2];
#pragma unroll
    for (int nb = 0; nb < 2; ++nb)
#pragma unroll
      for (int r = 0; r < 4; ++r) {
        const int bb = 4*q + r, col = 32*w + nb*16 + ln;
        acc[nb][r] = S2[(size_t)(bb*8 + m) * 256 + col];
      }
#pragma unroll
    for (int kk = 0; kk < 8; ++kk)
#pragma unroll
      for (int nb = 0; nb < 2; ++nb) {
        acc[nb] = __builtin_amdgcn_mfma_f32_16x16x32_bf16(ahi[kk], bhi[kk][nb], acc[nb], 0, 0, 0);
        acc[nb] = __builtin_amdgcn_mfma_f32_16x16x32_bf16(alo[kk], bhi[kk][nb], acc[nb], 0, 0, 0);
        acc[nb] = __builtin_amdgcn_mfma_f32_16x16x32_bf16(ahi[kk], blo[kk][nb], acc[nb], 0, 0, 0);
      }
#pragma unroll
    for (int nb = 0; nb < 2; ++nb)
#pragma unroll
      for (int r = 0; r < 4; ++r) {
        const int bb = 4*q + r, col = 32*w + nb*16 + ln;
        float v = acc[nb][r];
        unsigned short hi = f2u(v);
        Hhi[bb][col] = hi;
        Hlo[bb][col] = f2u(v - u2f(hi));
      }
    lds_barrier();
  }
}

// ---------------------------------------------------------------------------
extern "C" void kernel_launch(void* const* d_in, const int* in_sizes, int n_in,
                              void* d_out, int out_size, void* d_ws, size_t ws_size,
                              hipStream_t stream)
{
  const float* x   = (const float*)d_in[0];
  const float* Bm  = (const float*)d_in[1];
  const float* Lam = (const float*)d_in[2];
  float* Out = (float*)d_out;
  (void)in_sizes; (void)n_in; (void)out_size; (void)ws_size;

  char* ws = (char*)d_ws;
  size_t off = 0;
  auto alloc = [&](size_t bytes) { void* p = ws + off; off += (bytes + 255) & ~(size_t)255; return p; };
  unsigned short* Bx    = (unsigned short*)alloc((size_t)16777216 * 2);      // 32 MB
  unsigned short* Phi   = (unsigned short*)alloc((size_t)65 * 65536 * 2);    // 8.3 MB
  unsigned short* Plo   = (unsigned short*)alloc((size_t)65 * 65536 * 2);    // 8.3 MB
  unsigned short* Ghat  = (unsigned short*)alloc((size_t)16384 * 256 * 2);   // 8 MB
  unsigned short* Q     = (unsigned short*)alloc((size_t)256 * 16384 * 2);   // 8 MB
  unsigned short* Qcat  = (unsigned short*)alloc((size_t)2304 * 2048 * 2);   // 9.4 MB
  unsigned short* G2    = (unsigned short*)alloc((size_t)2048 * 256 * 2);    // 1 MB
  unsigned short* Phi2  = (unsigned short*)alloc((size_t)9 * 65536 * 2);
  unsigned short* Plo2  = (unsigned short*)alloc((size_t)9 * 65536 * 2);
  unsigned short* Bt    = (unsigned short*)alloc(131072);
  unsigned short* LamT  = (unsigned short*)alloc(131072);
  unsigned short* LcT2hi= (unsigned short*)alloc(131072);
  unsigned short* LcT2lo= (unsigned short*)alloc(131072);
  unsigned short* Acat  = (unsigned short*)alloc((size_t)128 * 2304 * 2);    // 0.6 MB
  float*          S2    = (float*)alloc(131072);
  unsigned short* Abf   = (unsigned short*)alloc(524288);
  unsigned int*   cnt   = (unsigned int*)alloc(256);                         // barrier counters
  float*          Spart = (float*)Plo;  // alias: Plo dead before summary phase writes Spart

  // 1) packs + P0/P1 (+ zero mega barrier counters — replay-safe)
  pack_init<<<dim3(256), dim3(256), 0, stream>>>(Bm, Lam, Bt, LamT, Phi, Plo, cnt);
  // 2) Bx = x @ B^T  (bf16 out)
  gemm_tile<true, true, false><<<dim3(4, 1024, 1), dim3(256), 0, stream>>>(
      (const void*)x, Bt, (void*)Bx, 256, 256, 256, 256, 0);
  // 3) MEGA: local scans (blocks 0..255) || power/pack/summary chain (256..511)
  mega<<<dim3(512), dim3(256), 0, stream>>>(LamT, Bx, Out,
      Phi, Plo, Phi2, Plo2, Ghat, Q, Qcat, G2, LcT2hi, LcT2lo, Spart, Acat, cnt);
  // 4) level-2 summaries: S2[128,256] = Acat_S[128,2048] @ G2
  gemm_tile<false, false, false><<<dim3(4, 2, 1), dim3(256), 0, stream>>>(
      (const void*)(Acat + 256), G2, (void*)S2, 2304, 256, 256, 2048, 0);
  // 5) sequential combine over 8 superchunks -> A2 into Acat cols 0..255
  k4b_combine<<<dim3(1), dim3(512), 0, stream>>>(LcT2hi, LcT2lo, S2, Acat);
  // 6) all chunk-entry states in one GEMM: Abf[128,2048] = Acat[128,2304] @ Qcat
  gemm_tile<false, true, false><<<dim3(32, 2, 1), dim3(256), 0, stream>>>(
      (const void*)Acat, Qcat, (void*)Abf, 2304, 2048, 2048, 2304, 0);
  // 7) carry GEMM with += epilogue: Out = Abf @ Q + Out(g_local)
  gemm_tile<false, false, true><<<dim3(256, 16, 1), dim3(256), 0, stream>>>(
      (const void*)Abf, Q, (void*)Out, 256, 16384, 16384, 256, 0);
}

// Round 4
// 805.537 us; speedup vs baseline: 1.8459x; 1.0962x over previous
//
#include <hip/hip_runtime.h>
#include <hip/hip_bf16.h>
#include <stdint.h>

// Problem: h_t = Lam @ h_{t-1} + B @ x_t ; BS=16, T=4096, D=256, fp32 in/out.
// Two-level chunked scan: level-1 chunks c=64, level-2 superchunks of 8.
// R6: SPATIAL fusion. R3-R5 proved temporal CU-sharing between the scan's
// serial chain and the pow group is destructive (time ~ sum, not max).
// The scan's 16x256 MFMA A-tile had 12 zero rows -> pack 16 chunks/block
// (same per-step instruction stream, bitwise-identical numerics) => scan
// needs only 64 blocks. Mega = 256 blocks (64 scan + 192 pow) at <=1
// block/CU: scan and pow land on DIFFERENT CUs (round-robin dispatch),
// eliminating arbitration interference while still hiding the pow chain.

#define CHUNK 64
#define NPB   192   // pow-group block count

typedef short v8s __attribute__((ext_vector_type(8)));   // 8 x bf16 (4 VGPRs)
typedef float v4f __attribute__((ext_vector_type(4)));   // MFMA accum

static __device__ __forceinline__ unsigned short f2u(float f) {
  union { float f; unsigned int u; } x; x.f = f;
  unsigned int u = x.u + 0x7FFFu + ((x.u >> 16) & 1u);   // RNE f32->bf16
  return (unsigned short)(u >> 16);
}
static __device__ __forceinline__ float u2f(unsigned short h) {
  union { unsigned int u; float f; } x; x.u = ((unsigned int)h) << 16;
  return x.f;
}
// Workgroup barrier that only drains LDS (lgkmcnt), leaving vmcnt free-running
// so register prefetch loads survive across it.
static __device__ __forceinline__ void lds_barrier() {
  asm volatile("s_waitcnt lgkmcnt(0)\n\ts_barrier" ::: "memory");
}
// Device-scope barrier among the NPB pow-group blocks. One counter per phase
// (no reset during the kernel -> no reset race); counters are zeroed by
// pack_init at the head of every launch/replay.
static __device__ __forceinline__ void gbar(unsigned* c) {
  __threadfence();
  __syncthreads();
  if (threadIdx.x == 0) {
    atomicAdd(c, 1u);
    while (__hip_atomic_load(c, __ATOMIC_RELAXED, __HIP_MEMORY_SCOPE_AGENT) < NPB)
      __builtin_amdgcn_s_sleep(2);
    __threadfence();
  }
  __syncthreads();
}

// ---------------------------------------------------------------------------
// Generic 64x64-tile bf16 MFMA GEMM. A: f32 or bf16 row-major [M,K] (lda).
// B: bf16 row-major [K,N] (ldb). C: f32 or bf16 [M,N] (ldc).
// blockIdx = (n_tile, m_tile, k_split). Per-split K length = Kper.
// Split partials go to C + z*csplit (f32 path only). ADD_C: C += A*B (f32).
// ---------------------------------------------------------------------------
template<bool A_F32, bool C_BF16, bool ADD_C>
__global__ __launch_bounds__(256) void gemm_tile(
    const void* __restrict__ Ap, const unsigned short* __restrict__ Bp,
    void* __restrict__ Cp, int lda, int ldb, int ldc, int Kper, long csplit)
{
  __shared__ unsigned short As[64][72];   // [m][k], pad to kill bank conflicts
  __shared__ unsigned short Bst[64][72];  // [n][k] (transposed for b128 frag reads)
  const int tid = threadIdx.x;
  const int lane = tid & 63, w = tid >> 6;       // 4 waves
  const int q = lane >> 4, ln = lane & 15;
  const long n0 = (long)blockIdx.x * 64;
  const long m0 = (long)blockIdx.y * 64;
  const int  kz = blockIdx.z;
  const long kbase = (long)kz * Kper;
  const int sm = tid >> 2;          // staging row 0..63
  const int sk = (tid & 3) << 4;    // staging col 0,16,32,48

  v4f acc[4];
#pragma unroll
  for (int i = 0; i < 4; ++i) acc[i] = 0;

  for (int ks = 0; ks < Kper; ks += 64) {
    const long kg = kbase + ks;
    __syncthreads();
    if (A_F32) {
      const float* A = (const float*)Ap + (m0 + sm) * (long)lda + kg + sk;
      float4 f[4];
#pragma unroll
      for (int t = 0; t < 4; ++t) f[t] = ((const float4*)A)[t];
      unsigned short* d = &As[sm][sk];
#pragma unroll
      for (int t = 0; t < 4; ++t) {
        d[4*t+0] = f2u(f[t].x); d[4*t+1] = f2u(f[t].y);
        d[4*t+2] = f2u(f[t].z); d[4*t+3] = f2u(f[t].w);
      }
    } else {
      const unsigned short* A = (const unsigned short*)Ap + (m0 + sm) * (long)lda + kg + sk;
      v8s t0 = ((const v8s*)A)[0], t1 = ((const v8s*)A)[1];
      *(v8s*)&As[sm][sk] = t0; *(v8s*)&As[sm][sk + 8] = t1;
    }
    // stage B (transpose into [n][k])
    {
      const unsigned short* Bg = Bp + (kg + sm) * (long)ldb + n0 + sk;
      v8s b0 = ((const v8s*)Bg)[0], b1 = ((const v8s*)Bg)[1];
#pragma unroll
      for (int r = 0; r < 8; ++r) Bst[sk + r][sm] = (unsigned short)b0[r];
#pragma unroll
      for (int r = 0; r < 8; ++r) Bst[sk + 8 + r][sm] = (unsigned short)b1[r];
    }
    __syncthreads();
#pragma unroll
    for (int kb = 0; kb < 64; kb += 32) {
      v8s a = *(const v8s*)&As[w*16 + ln][kb + q*8];
#pragma unroll
      for (int nb = 0; nb < 4; ++nb) {
        v8s b = *(const v8s*)&Bst[nb*16 + ln][kb + q*8];
        acc[nb] = __builtin_amdgcn_mfma_f32_16x16x32_bf16(a, b, acc[nb], 0, 0, 0);
      }
    }
  }
#pragma unroll
  for (int nb = 0; nb < 4; ++nb)
#pragma unroll
    for (int r = 0; r < 4; ++r) {
      const long row = m0 + w*16 + q*4 + r;        // D row = 4q+r within wave's 16
      const long col = n0 + nb*16 + ln;
      float v = acc[nb][r];
      if (C_BF16) ((unsigned short*)Cp)[row * (long)ldc + col] = f2u(v);
      else {
        float* Cf = (float*)Cp + (long)kz * csplit;
        if (ADD_C) v += Cf[row * (long)ldc + col];
        Cf[row * (long)ldc + col] = v;
      }
    }
}

// ---------------------------------------------------------------------------
// pack_init: Bt[e][d]=B[d][e], LamT[e][d]=Lam[d][e] (bf16); P_0=I, P_1=Lam hi/lo.
// Also zeroes the mega-kernel barrier counters (replay-safe).
// ---------------------------------------------------------------------------
__global__ __launch_bounds__(256) void pack_init(
    const float* __restrict__ Bm, const float* __restrict__ Lam,
    unsigned short* __restrict__ Bt, unsigned short* __restrict__ LamT,
    unsigned short* __restrict__ Phi, unsigned short* __restrict__ Plo,
    unsigned int* __restrict__ cnt)
{
  if (blockIdx.x == 0 && threadIdx.x < 16) cnt[threadIdx.x] = 0;
  const int idx = blockIdx.x * 256 + threadIdx.x;  // 0..65535
  const int e = idx >> 8, d = idx & 255;
  Bt[idx]   = f2u(Bm[d * 256 + e]);
  LamT[idx] = f2u(Lam[d * 256 + e]);
  float v = Lam[idx];                              // idx as (dd,ee) row-major
  unsigned short hi = f2u(v);
  Phi[65536 + idx] = hi;
  Plo[65536 + idx] = f2u(v - u2f(hi));
  const int dd = idx >> 8, ee = idx & 255;
  Phi[idx] = (dd == ee) ? (unsigned short)0x3F80 : (unsigned short)0;
  Plo[idx] = 0;
}

// ---------------------------------------------------------------------------
// Pow-job: P_{mpow+jj} = P_mpow * P_jj, split-bf16 (hi+lo):
// acc = Ah*Bh + Al*Bh + Ah*Bl (drops lo*lo) -> ~fp32. One 64x64 output tile.
// job encodes (jj, n0, m0); jobs per round = 16*mpow.
// ---------------------------------------------------------------------------
static __device__ void pow_job(unsigned short* __restrict__ Phi,
                               unsigned short* __restrict__ Plo,
                               int mpow, int job, char* smem)
{
  unsigned short (*As)[72]  = (unsigned short(*)[72])smem;
  unsigned short (*Bst)[72] = (unsigned short(*)[72])(smem + 9216);
  const int tid = threadIdx.x, lane = tid & 63, w = tid >> 6;
  const int q = lane >> 4, ln = lane & 15;
  const int jj = (job >> 4) + 1;
  const int n0 = (job & 3) * 64;
  const int m0 = ((job >> 2) & 3) * 64;
  const unsigned short* Ah = Phi + (size_t)mpow * 65536;
  const unsigned short* Al = Plo + (size_t)mpow * 65536;
  const unsigned short* Bh = Phi + (size_t)jj * 65536;
  const unsigned short* Bl = Plo + (size_t)jj * 65536;
  const int sm = tid >> 2, sk = (tid & 3) << 4;
  v4f acc[4];
#pragma unroll
  for (int i = 0; i < 4; ++i) acc[i] = 0;

  for (int seg = 0; seg < 3; ++seg) {
    const unsigned short* Asrc = (seg == 1) ? Al : Ah;
    const unsigned short* Bsrc = (seg == 2) ? Bl : Bh;
    for (int ks = 0; ks < 256; ks += 64) {
      __syncthreads();
      {
        const unsigned short* Ag = Asrc + (size_t)(m0 + sm) * 256 + ks + sk;
        v8s t0 = ((const v8s*)Ag)[0], t1 = ((const v8s*)Ag)[1];
        *(v8s*)&As[sm][sk] = t0; *(v8s*)&As[sm][sk + 8] = t1;
      }
      {
        const unsigned short* Bg = Bsrc + (size_t)(ks + sm) * 256 + n0 + sk;
        v8s b0 = ((const v8s*)Bg)[0], b1 = ((const v8s*)Bg)[1];
#pragma unroll
        for (int r = 0; r < 8; ++r) Bst[sk + r][sm] = (unsigned short)b0[r];
#pragma unroll
        for (int r = 0; r < 8; ++r) Bst[sk + 8 + r][sm] = (unsigned short)b1[r];
      }
      __syncthreads();
#pragma unroll
      for (int kb = 0; kb < 64; kb += 32) {
        v8s a = *(const v8s*)&As[w*16 + ln][kb + q*8];
#pragma unroll
        for (int nb = 0; nb < 4; ++nb) {
          v8s bb = *(const v8s*)&Bst[nb*16 + ln][kb + q*8];
          acc[nb] = __builtin_amdgcn_mfma_f32_16x16x32_bf16(a, bb, acc[nb], 0, 0, 0);
        }
      }
    }
  }
  const size_t ob = (size_t)(mpow + jj) * 65536;
#pragma unroll
  for (int nb = 0; nb < 4; ++nb)
#pragma unroll
    for (int r = 0; r < 4; ++r) {
      const int row = m0 + w*16 + q*4 + r;
      const int col = n0 + nb*16 + ln;
      float v = acc[nb][r];
      unsigned short hi = f2u(v);
      Phi[ob + (size_t)row*256 + col] = hi;
      Plo[ob + (size_t)row*256 + col] = f2u(v - u2f(hi));
    }
}

// ---------------------------------------------------------------------------
// pack_all job (job = 0..3359), identical indexing to the old pack_all kernel:
//  job<2048:  Ghat[(j*256+e)][d] = P_{63-j}[d][e];  Q[e][(j*256+d)] = P_{j+1}[d][e]
//  else:      Qcat[2304][2048], G2[2048][256], LcT2hi/lo[e][d] = P2_8[d][e]
// ---------------------------------------------------------------------------
static __device__ void pack_all_job(int blk0, char* smem,
    const unsigned short* __restrict__ Phi,
    const unsigned short* __restrict__ Phi2, const unsigned short* __restrict__ Plo2,
    unsigned short* __restrict__ Ghat, unsigned short* __restrict__ Q,
    unsigned short* __restrict__ Qcat, unsigned short* __restrict__ G2,
    unsigned short* __restrict__ LcT2hi, unsigned short* __restrict__ LcT2lo)
{
  unsigned short (*tile)[65] = (unsigned short(*)[65])smem;
  const int tx = threadIdx.x & 63, ty = threadIdx.x >> 6;  // ty 0..3
  if (blk0 < 2048) {
    const int blk = blk0;
    int t16, jpar;
    const unsigned short* src;
    if (blk < 1024) { jpar = blk >> 4;            t16 = blk & 15;  src = Phi + (size_t)(63 - jpar) * 65536; }
    else            { int v = blk - 1024; jpar = v >> 4; t16 = v & 15; src = Phi + (size_t)(jpar + 1) * 65536; }
    const int d0 = (t16 & 3) * 64, e0 = (t16 >> 2) * 64;
#pragma unroll
    for (int s = 0; s < 16; ++s)
      tile[ty*16 + s][tx] = src[(size_t)(d0 + ty*16 + s) * 256 + e0 + tx];
    __syncthreads();
    if (blk < 1024) {
#pragma unroll
      for (int s = 0; s < 16; ++s) {
        const int e = e0 + ty*16 + s, d = d0 + tx;
        Ghat[((size_t)(jpar*256 + e)) * 256 + d] = tile[tx][ty*16 + s];
      }
    } else {
#pragma unroll
      for (int s = 0; s < 16; ++s) {
        const int e = e0 + ty*16 + s, d = d0 + tx;
        Q[(size_t)e * 16384 + jpar*256 + d] = tile[tx][ty*16 + s];
      }
    }
  } else {
    const int blk = blk0 - 2048;
    if (blk < 1152) {                                // Qcat: 36x32 tiles of 64x64
      const int rt = blk >> 5, ct = blk & 31;
      const int k0 = rt * 64, c0 = ct * 64;
      const int r = c0 >> 8, d0 = c0 & 255;
      int p = 0, e0 = 0;
      bool zero = false;
      if (k0 < 256) { p = r; e0 = k0; }
      else {
        const int u = (k0 - 256) >> 8; e0 = (k0 - 256) & 255;
        if (u >= r) zero = true; else p = r - 1 - u;
      }
      if (zero) {
#pragma unroll
        for (int s = 0; s < 16; ++s)
          Qcat[(size_t)(k0 + ty*16 + s) * 2048 + c0 + tx] = 0;
      } else {
        const unsigned short* src = Phi2 + (size_t)p * 65536;
#pragma unroll
        for (int s = 0; s < 16; ++s)
          tile[ty*16 + s][tx] = src[(size_t)(d0 + ty*16 + s) * 256 + e0 + tx];
        __syncthreads();
#pragma unroll
        for (int s = 0; s < 16; ++s)
          Qcat[(size_t)(k0 + ty*16 + s) * 2048 + c0 + tx] = tile[tx][ty*16 + s];
      }
    } else if (blk < 1280) {                         // G2: 32x4 tiles
      const int t = blk - 1152;
      const int rt = t >> 2, ct = t & 3;
      const int k0 = rt * 64, d0 = ct * 64;
      const int r = k0 >> 8, e0 = k0 & 255;
      const unsigned short* src = Phi2 + (size_t)(7 - r) * 65536;
#pragma unroll
      for (int s = 0; s < 16; ++s)
        tile[ty*16 + s][tx] = src[(size_t)(d0 + ty*16 + s) * 256 + e0 + tx];
      __syncthreads();
#pragma unroll
      for (int s = 0; s < 16; ++s)
        G2[(size_t)(k0 + ty*16 + s) * 256 + d0 + tx] = tile[tx][ty*16 + s];
    } else {                                         // LcT2 hi (16) + lo (16)
      const int t = blk - 1280;
      const int half = t >> 4, t16 = t & 15;
      const int d0 = (t16 & 3) * 64, e0 = (t16 >> 2) * 64;
      const unsigned short* src = (half ? Plo2 : Phi2) + (size_t)8 * 65536;
      unsigned short* dst = half ? LcT2lo : LcT2hi;
#pragma unroll
      for (int s = 0; s < 16; ++s)
        tile[ty*16 + s][tx] = src[(size_t)(d0 + ty*16 + s) * 256 + e0 + tx];
      __syncthreads();
#pragma unroll
      for (int s = 0; s < 16; ++s)
        dst[(size_t)(e0 + ty*16 + s) * 256 + d0 + tx] = tile[tx][ty*16 + s];
    }
  }
  __syncthreads();   // protect LDS tile reuse by the next job
}

// ---------------------------------------------------------------------------
// Chunk-summary GEMM job: S = Bx_r[1024,16384] @ Ghat[16384,256], split-K=8.
// job = 0..511: nz = job&3, my = (job>>2)&15, kz = job>>6.  Kper=2048.
// ---------------------------------------------------------------------------
static __device__ void sum_job(int job, char* smem,
    const unsigned short* __restrict__ Bx, const unsigned short* __restrict__ Ghat,
    float* __restrict__ Spart)
{
  unsigned short (*As)[72]  = (unsigned short(*)[72])smem;
  unsigned short (*Bst)[72] = (unsigned short(*)[72])(smem + 9216);
  const int tid = threadIdx.x, lane = tid & 63, w = tid >> 6;
  const int q = lane >> 4, ln = lane & 15;
  const long n0 = (long)(job & 3) * 64;
  const long m0 = (long)((job >> 2) & 15) * 64;
  const int  kz = job >> 6;
  const long kbase = (long)kz * 2048;
  const int sm = tid >> 2, sk = (tid & 3) << 4;
  v4f acc[4];
#pragma unroll
  for (int i = 0; i < 4; ++i) acc[i] = 0;

  for (int ks = 0; ks < 2048; ks += 64) {
    const long kg = kbase + ks;
    __syncthreads();
    {
      const unsigned short* A = Bx + (m0 + sm) * 16384L + kg + sk;
      v8s t0 = ((const v8s*)A)[0], t1 = ((const v8s*)A)[1];
      *(v8s*)&As[sm][sk] = t0; *(v8s*)&As[sm][sk + 8] = t1;
    }
    {
      const unsigned short* Bg = Ghat + (kg + sm) * 256L + n0 + sk;
      v8s b0 = ((const v8s*)Bg)[0], b1 = ((const v8s*)Bg)[1];
#pragma unroll
      for (int r = 0; r < 8; ++r) Bst[sk + r][sm] = (unsigned short)b0[r];
#pragma unroll
      for (int r = 0; r < 8; ++r) Bst[sk + 8 + r][sm] = (unsigned short)b1[r];
    }
    __syncthreads();
#pragma unroll
    for (int kb = 0; kb < 64; kb += 32) {
      v8s a = *(const v8s*)&As[w*16 + ln][kb + q*8];
#pragma unroll
      for (int nb = 0; nb < 4; ++nb) {
        v8s b = *(const v8s*)&Bst[nb*16 + ln][kb + q*8];
        acc[nb] = __builtin_amdgcn_mfma_f32_16x16x32_bf16(a, b, acc[nb], 0, 0, 0);
      }
    }
  }
#pragma unroll
  for (int nb = 0; nb < 4; ++nb)
#pragma unroll
    for (int r = 0; r < 4; ++r) {
      const long row = m0 + w*16 + q*4 + r;
      const long col = n0 + nb*16 + ln;
      Spart[(long)kz * 262144 + row * 256 + col] = acc[nb][r];
    }
}

// ---------------------------------------------------------------------------
// MEGA kernel (256 blocks x 256 threads, <=1 block/CU -> spatial partition):
//  blocks 0..63   : scan, 16 chunks/block (full 16-row MFMA A-tile; same
//                   per-step instruction stream as the old 4-chunk scan,
//                   bitwise-identical per-chunk numerics).
//  blocks 64..255 : pow group (192 blocks) — level-1 doubling (6 rounds) ->
//                   pack2 -> level-2 doubling (3 rounds) -> pack_all ->
//                   summary GEMM -> reduce_s2, device barriers between phases.
// Different CUs for the two groups under round-robin dispatch => no
// scheduler interference (R3-R5's failure mode). Co-residency for gbar is
// guaranteed: 256 blocks <= 256 CUs at >=1 block/CU capacity.
// ---------------------------------------------------------------------------
__global__ __launch_bounds__(256) void mega(
    const unsigned short* __restrict__ LamT, const unsigned short* __restrict__ Bx,
    float* __restrict__ Out,
    unsigned short* __restrict__ Phi,  unsigned short* __restrict__ Plo,
    unsigned short* __restrict__ Phi2, unsigned short* __restrict__ Plo2,
    unsigned short* __restrict__ Ghat, unsigned short* __restrict__ Q,
    unsigned short* __restrict__ Qcat, unsigned short* __restrict__ G2,
    unsigned short* __restrict__ LcT2hi, unsigned short* __restrict__ LcT2lo,
    float* __restrict__ Spart, unsigned short* __restrict__ Acat,
    unsigned int* __restrict__ cnt)
{
  __shared__ __align__(16) char smem[18432];   // max(scan 8448, pow 18432, pack 8320)
  const int tid = threadIdx.x;

  if (blockIdx.x < 64) {
    // ------------- scan path: 16 chunks per block, 64 blocks -------------
    unsigned short (*gs)[264] = (unsigned short(*)[264])smem;
    const int lane = tid & 63, w = tid >> 6;  // 4 waves
    const int q = lane >> 4, ln = lane & 15;
    const int blk = blockIdx.x;
    const int b  = blk >> 2;            // batch 0..15
    const int i0 = (blk & 3) * 16;      // first chunk index (16 chunks/block)
    const int rq = 4 * q;               // this lane's first gs row

    v8s bf[8][4];                        // Lam^T frags, cols [64w,64w+64)
#pragma unroll
    for (int kk = 0; kk < 8; ++kk)
#pragma unroll
      for (int nb = 0; nb < 4; ++nb) {
        const int n = 64*w + nb*16 + ln;
#pragma unroll
        for (int r = 0; r < 8; ++r)
          bf[kk][nb][r] = (short)LamT[(kk*32 + q*8 + r) * 256 + n];
      }
    for (int e = tid; e < 16*264; e += 256) (&gs[0][0])[e] = 0;

    // chunk (i0+k) state lives in gs row k; row k of MFMA D = chunk i0+k.
    const size_t base0 = ((size_t)b*4096 + (size_t)i0*64) * 256;  // j=0 of chunk i0
    const int colw = 64*w;

    unsigned short bxr[2][4][4];         // depth-2 Bx prefetch ring (ALL lanes)
#pragma unroll
    for (int s = 0; s < 2; ++s)
#pragma unroll
      for (int r = 0; r < 4; ++r)
#pragma unroll
        for (int nb = 0; nb < 4; ++nb)
          bxr[s][r][nb] = Bx[base0 + (size_t)(rq + r)*16384 + (size_t)s*256 + colw + nb*16 + ln];
    lds_barrier();

#pragma unroll 2
    for (int j = 0; j < CHUNK; ++j) {
      v8s a[8];
#pragma unroll
      for (int kk = 0; kk < 8; ++kk) a[kk] = *(const v8s*)&gs[ln][kk*32 + q*8];
      lds_barrier();
      v4f acc[4];
#pragma unroll
      for (int nb = 0; nb < 4; ++nb) acc[nb] = 0;
#pragma unroll
      for (int kk = 0; kk < 8; ++kk)
#pragma unroll
        for (int nb = 0; nb < 4; ++nb)
          acc[nb] = __builtin_amdgcn_mfma_f32_16x16x32_bf16(a[kk], bf[kk][nb], acc[nb], 0, 0, 0);
#pragma unroll
      for (int r = 0; r < 4; ++r) {
        const size_t rb = base0 + (size_t)(rq + r)*16384 + (size_t)j*256 + colw;
#pragma unroll
        for (int nb = 0; nb < 4; ++nb) {
          const float g = acc[nb][r] + u2f(bxr[j & 1][r][nb]);
          Out[rb + nb*16 + ln] = g;
          gs[rq + r][colw + nb*16 + ln] = f2u(g);
        }
      }
      if (j < CHUNK - 2) {
#pragma unroll
        for (int r = 0; r < 4; ++r) {
          const size_t rb = base0 + (size_t)(rq + r)*16384 + (size_t)(j + 2)*256 + colw;
#pragma unroll
          for (int nb = 0; nb < 4; ++nb)
            bxr[j & 1][r][nb] = Bx[rb + nb*16 + ln];
        }
      }
      lds_barrier();
    }
    return;
  }

  // ---------------- pow group (192 blocks) ----------------
  const int pid = (int)blockIdx.x - 64;
  int bar = 0;
  // level-1 powers P_2..P_64 by doubling (6 rounds)
#pragma unroll 1
  for (int mp = 1; mp <= 32; mp <<= 1) {
    for (int job = pid; job < 16 * mp; job += NPB)
      pow_job(Phi, Plo, mp, job, smem);
    gbar(&cnt[bar++]);
  }
  // pack2: P2_0 = I, P2_1 = P_64 (hi/lo)
  for (int idx = pid * 256 + tid; idx < 65536; idx += NPB * 256) {
    const int dd = idx >> 8, ee = idx & 255;
    Phi2[idx] = (dd == ee) ? (unsigned short)0x3F80 : (unsigned short)0;
    Plo2[idx] = 0;
    Phi2[65536 + idx] = Phi[(size_t)64 * 65536 + idx];
    Plo2[65536 + idx] = Plo[(size_t)64 * 65536 + idx];
  }
  gbar(&cnt[bar++]);
  // level-2 powers P2_2..P2_8 (3 rounds)
#pragma unroll 1
  for (int mp = 1; mp <= 4; mp <<= 1) {
    for (int job = pid; job < 16 * mp; job += NPB)
      pow_job(Phi2, Plo2, mp, job, smem);
    gbar(&cnt[bar++]);
  }
  // pack all GEMM operands
  for (int job = pid; job < 3360; job += NPB)
    pack_all_job(job, smem, Phi, Phi2, Plo2, Ghat, Q, Qcat, G2, LcT2hi, LcT2lo);
  gbar(&cnt[bar++]);
  // chunk summaries: S = Bx_r[1024,16384] @ Ghat (split-K=8 -> Spart)
  for (int job = pid; job < 512; job += NPB)
    sum_job(job, smem, Bx, Ghat, Spart);
  gbar(&cnt[bar++]);
  // reduce split-K partials and scatter into Acat S-region
  for (int job = pid; job < 1024; job += NPB) {
    const int f = job * 256 + tid;
    float v = 0;
#pragma unroll
    for (int z = 0; z < 8; ++z) v += Spart[(size_t)z * 262144 + f];
    const int e = f & 255, i = (f >> 8) & 63, bb = f >> 14;
    const int u = i & 7, m = i >> 3;
    Acat[(size_t)(bb*8 + m) * 2304 + 256 + u*256 + e] = f2u(v);
  }
}

// ---------------------------------------------------------------------------
// Level-2 sequential combine: 8 steps, ONE workgroup, split-bf16 MFMA.
// A2_{b,m} (state entering superchunk m) written bf16 into Acat cols 0..255.
// ---------------------------------------------------------------------------
__global__ __launch_bounds__(512, 2) void k4b_combine(
    const unsigned short* __restrict__ LcT2hi, const unsigned short* __restrict__ LcT2lo,
    const float* __restrict__ S2, unsigned short* __restrict__ Acat)
{
  __shared__ unsigned short Hhi[16][264];
  __shared__ unsigned short Hlo[16][264];
  const int tid = threadIdx.x, lane = tid & 63, w = tid >> 6;  // 8 waves
  const int q = lane >> 4, ln = lane & 15;

  v8s bhi[8][2], blo[8][2];                       // (Lam^512)^T frags, cols [32w,32w+32)
#pragma unroll
  for (int kk = 0; kk < 8; ++kk)
#pragma unroll
    for (int nb = 0; nb < 2; ++nb) {
      const int n = 32*w + nb*16 + ln;
#pragma unroll
      for (int r = 0; r < 8; ++r) {
        const int k = kk*32 + q*8 + r;
        bhi[kk][nb][r] = (short)LcT2hi[k*256 + n];
        blo[kk][nb][r] = (short)LcT2lo[k*256 + n];
      }
    }
  for (int e = tid; e < 16*264; e += 512) { (&Hhi[0][0])[e] = 0; (&Hlo[0][0])[e] = 0; }
  lds_barrier();

  for (int m = 0; m < 8; ++m) {
    // A2_{b,m} = state BEFORE absorbing superchunk m
    for (int e = tid; e < 4096; e += 512) {
      const int b = e >> 8, d = e & 255;
      Acat[(size_t)(b*8 + m) * 2304 + d] = Hhi[b][d];
    }
    v8s ahi[8], alo[8];
#pragma unroll
    for (int kk = 0; kk < 8; ++kk) {
      ahi[kk] = *(const v8s*)&Hhi[ln][kk*32 + q*8];
      alo[kk] = *(const v8s*)&Hlo[ln][kk*32 + q*8];
    }
    lds_barrier();
    v4f acc[2];
#pragma unroll
    for (int nb = 0; nb < 2; ++nb)
#pragma unroll
      for (int r = 0; r < 4; ++r) {
        const int bb = 4*q + r, col = 32*w + nb*16 + ln;
        acc[nb][r] = S2[(size_t)(bb*8 + m) * 256 + col];
      }
#pragma unroll
    for (int kk = 0; kk < 8; ++kk)
#pragma unroll
      for (int nb = 0; nb < 2; ++nb) {
        acc[nb] = __builtin_amdgcn_mfma_f32_16x16x32_bf16(ahi[kk], bhi[kk][nb], acc[nb], 0, 0, 0);
        acc[nb] = __builtin_amdgcn_mfma_f32_16x16x32_bf16(alo[kk], bhi[kk][nb], acc[nb], 0, 0, 0);
        acc[nb] = __builtin_amdgcn_mfma_f32_16x16x32_bf16(ahi[kk], blo[kk][nb], acc[nb], 0, 0, 0);
      }
#pragma unroll
    for (int nb = 0; nb < 2; ++nb)
#pragma unroll
      for (int r = 0; r < 4; ++r) {
        const int bb = 4*q + r, col = 32*w + nb*16 + ln;
        float v = acc[nb][r];
        unsigned short hi = f2u(v);
        Hhi[bb][col] = hi;
        Hlo[bb][col] = f2u(v - u2f(hi));
      }
    lds_barrier();
  }
}

// ---------------------------------------------------------------------------
extern "C" void kernel_launch(void* const* d_in, const int* in_sizes, int n_in,
                              void* d_out, int out_size, void* d_ws, size_t ws_size,
                              hipStream_t stream)
{
  const float* x   = (const float*)d_in[0];
  const float* Bm  = (const float*)d_in[1];
  const float* Lam = (const float*)d_in[2];
  float* Out = (float*)d_out;
  (void)in_sizes; (void)n_in; (void)out_size; (void)ws_size;

  char* ws = (char*)d_ws;
  size_t off = 0;
  auto alloc = [&](size_t bytes) { void* p = ws + off; off += (bytes + 255) & ~(size_t)255; return p; };
  unsigned short* Bx    = (unsigned short*)alloc((size_t)16777216 * 2);      // 32 MB
  unsigned short* Phi   = (unsigned short*)alloc((size_t)65 * 65536 * 2);    // 8.3 MB
  unsigned short* Plo   = (unsigned short*)alloc((size_t)65 * 65536 * 2);    // 8.3 MB
  unsigned short* Ghat  = (unsigned short*)alloc((size_t)16384 * 256 * 2);   // 8 MB
  unsigned short* Q     = (unsigned short*)alloc((size_t)256 * 16384 * 2);   // 8 MB
  unsigned short* Qcat  = (unsigned short*)alloc((size_t)2304 * 2048 * 2);   // 9.4 MB
  unsigned short* G2    = (unsigned short*)alloc((size_t)2048 * 256 * 2);    // 1 MB
  unsigned short* Phi2  = (unsigned short*)alloc((size_t)9 * 65536 * 2);
  unsigned short* Plo2  = (unsigned short*)alloc((size_t)9 * 65536 * 2);
  unsigned short* Bt    = (unsigned short*)alloc(131072);
  unsigned short* LamT  = (unsigned short*)alloc(131072);
  unsigned short* LcT2hi= (unsigned short*)alloc(131072);
  unsigned short* LcT2lo= (unsigned short*)alloc(131072);
  unsigned short* Acat  = (unsigned short*)alloc((size_t)128 * 2304 * 2);    // 0.6 MB
  float*          S2    = (float*)alloc(131072);
  unsigned short* Abf   = (unsigned short*)alloc(524288);
  unsigned int*   cnt   = (unsigned int*)alloc(256);                         // barrier counters
  float*          Spart = (float*)Plo;  // alias: Plo dead before summary phase writes Spart

  // 1) packs + P0/P1 (+ zero mega barrier counters — replay-safe)
  pack_init<<<dim3(256), dim3(256), 0, stream>>>(Bm, Lam, Bt, LamT, Phi, Plo, cnt);
  // 2) Bx = x @ B^T  (bf16 out)
  gemm_tile<true, true, false><<<dim3(4, 1024, 1), dim3(256), 0, stream>>>(
      (const void*)x, Bt, (void*)Bx, 256, 256, 256, 256, 0);
  // 3) MEGA: scans on blocks 0..63 || power/pack/summary chain on 64..255
  mega<<<dim3(256), dim3(256), 0, stream>>>(LamT, Bx, Out,
      Phi, Plo, Phi2, Plo2, Ghat, Q, Qcat, G2, LcT2hi, LcT2lo, Spart, Acat, cnt);
  // 4) level-2 summaries: S2[128,256] = Acat_S[128,2048] @ G2
  gemm_tile<false, false, false><<<dim3(4, 2, 1), dim3(256), 0, stream>>>(
      (const void*)(Acat + 256), G2, (void*)S2, 2304, 256, 256, 2048, 0);
  // 5) sequential combine over 8 superchunks -> A2 into Acat cols 0..255
  k4b_combine<<<dim3(1), dim3(512), 0, stream>>>(LcT2hi, LcT2lo, S2, Acat);
  // 6) all chunk-entry states in one GEMM: Abf[128,2048] = Acat[128,2304] @ Qcat
  gemm_tile<false, true, false><<<dim3(32, 2, 1), dim3(256), 0, stream>>>(
      (const void*)Acat, Qcat, (void*)Abf, 2304, 2048, 2048, 2304, 0);
  // 7) carry GEMM with += epilogue: Out = Abf @ Q + Out(g_local)
  gemm_tile<false, false, true><<<dim3(256, 16, 1), dim3(256), 0, stream>>>(
      (const void*)Abf, Q, (void*)Out, 256, 16384, 16384, 256, 0);
}

// Round 5
// 433.389 us; speedup vs baseline: 3.4309x; 1.8587x over previous
//
#include <hip/hip_runtime.h>
#include <hip/hip_bf16.h>
#include <stdint.h>

// Problem: h_t = Lam @ h_{t-1} + B @ x_t ; BS=16, T=4096, D=256, fp32 in/out.
// Two-level chunked scan: level-1 chunks c=64 (C=64), level-2 superchunks of 8.
// R7: fusion abandoned (R3-R6: persistent pow chain is latency-serial at 1
// block/CU, ~3x slower than launches). Back to the 497us launch structure
// with three bit-exact local optimizations:
//  (a) k5_scan: double-buffered gs -> ONE lds_barrier per step (was 2).
//  (b) gemm_tile: register-prefetch next K-tile before MFMA phase (T14) so
//      HBM latency hides under MFMA instead of sitting between barriers.
//  (c) pow_round: same depth-1 pipelining over the flattened 12-iter loop.

#define CHUNK  64
#define NCHUNK 64

typedef short v8s __attribute__((ext_vector_type(8)));   // 8 x bf16 (4 VGPRs)
typedef float v4f __attribute__((ext_vector_type(4)));   // MFMA accum

static __device__ __forceinline__ unsigned short f2u(float f) {
  union { float f; unsigned int u; } x; x.f = f;
  unsigned int u = x.u + 0x7FFFu + ((x.u >> 16) & 1u);   // RNE f32->bf16
  return (unsigned short)(u >> 16);
}
static __device__ __forceinline__ float u2f(unsigned short h) {
  union { unsigned int u; float f; } x; x.u = ((unsigned int)h) << 16;
  return x.f;
}
// Workgroup barrier that only drains LDS (lgkmcnt), leaving vmcnt free-running
// so register prefetch loads survive across it. Safe when the only cross-wave
// dependency through the barrier is LDS data.
static __device__ __forceinline__ void lds_barrier() {
  asm volatile("s_waitcnt lgkmcnt(0)\n\ts_barrier" ::: "memory");
}

// ---------------------------------------------------------------------------
// Generic 64x64-tile bf16 MFMA GEMM, depth-1 software-pipelined staging.
// A: f32 or bf16 row-major [M,K] (lda). B: bf16 row-major [K,N] (ldb).
// C: f32 or bf16 [M,N] (ldc). blockIdx = (n_tile, m_tile, k_split).
// Per-split K length = Kper. Split partials go to C + z*csplit (f32 path).
// ADD_C: C += A*B (f32). Numerics identical to the unpipelined version.
// ---------------------------------------------------------------------------
template<bool A_F32, bool C_BF16, bool ADD_C>
__global__ __launch_bounds__(256) void gemm_tile(
    const void* __restrict__ Ap, const unsigned short* __restrict__ Bp,
    void* __restrict__ Cp, int lda, int ldb, int ldc, int Kper, long csplit)
{
  __shared__ unsigned short As[64][72];   // [m][k], pad to kill bank conflicts
  __shared__ unsigned short Bst[64][72];  // [n][k] (transposed for b128 frag reads)
  const int tid = threadIdx.x;
  const int lane = tid & 63, w = tid >> 6;       // 4 waves
  const int q = lane >> 4, ln = lane & 15;
  const long n0 = (long)blockIdx.x * 64;
  const long m0 = (long)blockIdx.y * 64;
  const int  kz = blockIdx.z;
  const long kbase = (long)kz * Kper;
  const int sm = tid >> 2;          // staging row 0..63
  const int sk = (tid & 3) << 4;    // staging col 0,16,32,48

  v4f acc[4];
#pragma unroll
  for (int i = 0; i < 4; ++i) acc[i] = 0;

  // staging registers (next K-tile in flight)
  float4 fA[4];
  v8s aR0, aR1, bR0, bR1;

  auto load_tile = [&](long kg) {
    if (A_F32) {
      const float* A = (const float*)Ap + (m0 + sm) * (long)lda + kg + sk;
#pragma unroll
      for (int t = 0; t < 4; ++t) fA[t] = ((const float4*)A)[t];
    } else {
      const unsigned short* A = (const unsigned short*)Ap + (m0 + sm) * (long)lda + kg + sk;
      aR0 = ((const v8s*)A)[0]; aR1 = ((const v8s*)A)[1];
    }
    const unsigned short* Bg = Bp + (kg + sm) * (long)ldb + n0 + sk;
    bR0 = ((const v8s*)Bg)[0]; bR1 = ((const v8s*)Bg)[1];
  };

  load_tile(kbase);                       // prologue: tile ks=0 in regs

  for (int ks = 0; ks < Kper; ks += 64) {
    __syncthreads();                      // prior MFMA phase done with LDS
    // write staged regs -> LDS
    if (A_F32) {
      unsigned short* d = &As[sm][sk];
#pragma unroll
      for (int t = 0; t < 4; ++t) {
        d[4*t+0] = f2u(fA[t].x); d[4*t+1] = f2u(fA[t].y);
        d[4*t+2] = f2u(fA[t].z); d[4*t+3] = f2u(fA[t].w);
      }
    } else {
      *(v8s*)&As[sm][sk] = aR0; *(v8s*)&As[sm][sk + 8] = aR1;
    }
#pragma unroll
    for (int r = 0; r < 8; ++r) Bst[sk + r][sm] = (unsigned short)bR0[r];
#pragma unroll
    for (int r = 0; r < 8; ++r) Bst[sk + 8 + r][sm] = (unsigned short)bR1[r];
    __syncthreads();
    // prefetch next tile into regs — overlaps with the MFMA phase below
    if (ks + 64 < Kper) load_tile(kbase + ks + 64);
#pragma unroll
    for (int kb = 0; kb < 64; kb += 32) {
      v8s a = *(const v8s*)&As[w*16 + ln][kb + q*8];
#pragma unroll
      for (int nb = 0; nb < 4; ++nb) {
        v8s b = *(const v8s*)&Bst[nb*16 + ln][kb + q*8];
        acc[nb] = __builtin_amdgcn_mfma_f32_16x16x32_bf16(a, b, acc[nb], 0, 0, 0);
      }
    }
  }
#pragma unroll
  for (int nb = 0; nb < 4; ++nb)
#pragma unroll
    for (int r = 0; r < 4; ++r) {
      const long row = m0 + w*16 + q*4 + r;        // D row = 4q+r within wave's 16
      const long col = n0 + nb*16 + ln;
      float v = acc[nb][r];
      if (C_BF16) ((unsigned short*)Cp)[row * (long)ldc + col] = f2u(v);
      else {
        float* Cf = (float*)Cp + (long)kz * csplit;
        if (ADD_C) v += Cf[row * (long)ldc + col];
        Cf[row * (long)ldc + col] = v;
      }
    }
}

// ---------------------------------------------------------------------------
// Powers by doubling, split-bf16 (hi+lo): P_{mpow+jj} = P_mpow * P_jj,
// jj=1..mpow.  acc = Ah*Bh + Al*Bh + Ah*Bl (drops lo*lo) -> ~fp32.
// Depth-1 pipelined over the flattened 12-iteration (seg,ks) loop.
// ---------------------------------------------------------------------------
__global__ __launch_bounds__(256) void pow_round(
    unsigned short* __restrict__ Phi, unsigned short* __restrict__ Plo, int mpow)
{
  __shared__ unsigned short As[64][72];
  __shared__ unsigned short Bst[64][72];
  const int tid = threadIdx.x, lane = tid & 63, w = tid >> 6;
  const int q = lane >> 4, ln = lane & 15;
  const int jj = (blockIdx.x >> 2) + 1;
  const int n0 = (blockIdx.x & 3) * 64;
  const int m0 = blockIdx.y * 64;
  const unsigned short* Ah = Phi + (size_t)mpow * 65536;
  const unsigned short* Al = Plo + (size_t)mpow * 65536;
  const unsigned short* Bh = Phi + (size_t)jj * 65536;
  const unsigned short* Bl = Plo + (size_t)jj * 65536;
  const int sm = tid >> 2, sk = (tid & 3) << 4;
  v4f acc[4];
#pragma unroll
  for (int i = 0; i < 4; ++i) acc[i] = 0;

  v8s aR0, aR1, bR0, bR1;
  auto load_tile = [&](int it) {
    const int seg = it >> 2, ks = (it & 3) << 6;
    const unsigned short* Asrc = (seg == 1) ? Al : Ah;
    const unsigned short* Bsrc = (seg == 2) ? Bl : Bh;
    const unsigned short* Ag = Asrc + (size_t)(m0 + sm) * 256 + ks + sk;
    aR0 = ((const v8s*)Ag)[0]; aR1 = ((const v8s*)Ag)[1];
    const unsigned short* Bg = Bsrc + (size_t)(ks + sm) * 256 + n0 + sk;
    bR0 = ((const v8s*)Bg)[0]; bR1 = ((const v8s*)Bg)[1];
  };

  load_tile(0);
  for (int it = 0; it < 12; ++it) {
    __syncthreads();
    *(v8s*)&As[sm][sk] = aR0; *(v8s*)&As[sm][sk + 8] = aR1;
#pragma unroll
    for (int r = 0; r < 8; ++r) Bst[sk + r][sm] = (unsigned short)bR0[r];
#pragma unroll
    for (int r = 0; r < 8; ++r) Bst[sk + 8 + r][sm] = (unsigned short)bR1[r];
    __syncthreads();
    if (it + 1 < 12) load_tile(it + 1);   // overlaps with MFMA below
#pragma unroll
    for (int kb = 0; kb < 64; kb += 32) {
      v8s a = *(const v8s*)&As[w*16 + ln][kb + q*8];
#pragma unroll
      for (int nb = 0; nb < 4; ++nb) {
        v8s bb = *(const v8s*)&Bst[nb*16 + ln][kb + q*8];
        acc[nb] = __builtin_amdgcn_mfma_f32_16x16x32_bf16(a, bb, acc[nb], 0, 0, 0);
      }
    }
  }
  const size_t ob = (size_t)(mpow + jj) * 65536;
#pragma unroll
  for (int nb = 0; nb < 4; ++nb)
#pragma unroll
    for (int r = 0; r < 4; ++r) {
      const int row = m0 + w*16 + q*4 + r;
      const int col = n0 + nb*16 + ln;
      float v = acc[nb][r];
      unsigned short hi = f2u(v);
      Phi[ob + (size_t)row*256 + col] = hi;
      Plo[ob + (size_t)row*256 + col] = f2u(v - u2f(hi));
    }
}

// ---------------------------------------------------------------------------
// pack_init: Bt[e][d]=B[d][e], LamT[e][d]=Lam[d][e] (bf16); P_0=I, P_1=Lam hi/lo.
// ---------------------------------------------------------------------------
__global__ __launch_bounds__(256) void pack_init(
    const float* __restrict__ Bm, const float* __restrict__ Lam,
    unsigned short* __restrict__ Bt, unsigned short* __restrict__ LamT,
    unsigned short* __restrict__ Phi, unsigned short* __restrict__ Plo)
{
  const int idx = blockIdx.x * 256 + threadIdx.x;  // 0..65535
  const int e = idx >> 8, d = idx & 255;
  Bt[idx]   = f2u(Bm[d * 256 + e]);
  LamT[idx] = f2u(Lam[d * 256 + e]);
  float v = Lam[idx];                              // idx as (dd,ee) row-major
  unsigned short hi = f2u(v);
  Phi[65536 + idx] = hi;
  Plo[65536 + idx] = f2u(v - u2f(hi));
  const int dd = idx >> 8, ee = idx & 255;
  Phi[idx] = (dd == ee) ? (unsigned short)0x3F80 : (unsigned short)0;
  Plo[idx] = 0;
}

// ---------------------------------------------------------------------------
// pack2_init: level-2 power table P2_j = Lam^(64j). P2_0=I, P2_1=P_64 (hi/lo).
// ---------------------------------------------------------------------------
__global__ __launch_bounds__(256) void pack2_init(
    const unsigned short* __restrict__ Phi, const unsigned short* __restrict__ Plo,
    unsigned short* __restrict__ Phi2, unsigned short* __restrict__ Plo2)
{
  const int idx = blockIdx.x * 256 + threadIdx.x;  // 0..65535
  const int dd = idx >> 8, ee = idx & 255;
  Phi2[idx] = (dd == ee) ? (unsigned short)0x3F80 : (unsigned short)0;
  Plo2[idx] = 0;
  Phi2[65536 + idx] = Phi[(size_t)64 * 65536 + idx];
  Plo2[65536 + idx] = Plo[(size_t)64 * 65536 + idx];
}

// ---------------------------------------------------------------------------
// pack_all: fused pack_g (blocks 0..2047) + pack_g2 (blocks 2048..3359).
//  pack_g:  Ghat[(j*256+e)][d] = P_{63-j}[d][e];  Q[e][(j*256+d)] = P_{j+1}[d][e]
//  pack_g2: Qcat[2304][2048], G2[2048][256], LcT2hi/lo[e][d] = P2_8[d][e]
// ---------------------------------------------------------------------------
__global__ __launch_bounds__(256) void pack_all(
    const unsigned short* __restrict__ Phi,
    const unsigned short* __restrict__ Phi2, const unsigned short* __restrict__ Plo2,
    unsigned short* __restrict__ Ghat, unsigned short* __restrict__ Q,
    unsigned short* __restrict__ Qcat, unsigned short* __restrict__ G2,
    unsigned short* __restrict__ LcT2hi, unsigned short* __restrict__ LcT2lo)
{
  __shared__ unsigned short tile[64][65];
  const int tx = threadIdx.x & 63, ty = threadIdx.x >> 6;  // ty 0..3
  const int blk0 = blockIdx.x;
  if (blk0 < 2048) {
    const int blk = blk0;
    int t16, jpar;
    const unsigned short* src;
    if (blk < 1024) { jpar = blk >> 4;            t16 = blk & 15;  src = Phi + (size_t)(63 - jpar) * 65536; }
    else            { int v = blk - 1024; jpar = v >> 4; t16 = v & 15; src = Phi + (size_t)(jpar + 1) * 65536; }
    const int d0 = (t16 & 3) * 64, e0 = (t16 >> 2) * 64;
#pragma unroll
    for (int s = 0; s < 16; ++s)
      tile[ty*16 + s][tx] = src[(size_t)(d0 + ty*16 + s) * 256 + e0 + tx];
    __syncthreads();
    if (blk < 1024) {
#pragma unroll
      for (int s = 0; s < 16; ++s) {
        const int e = e0 + ty*16 + s, d = d0 + tx;
        Ghat[((size_t)(jpar*256 + e)) * 256 + d] = tile[tx][ty*16 + s];
      }
    } else {
#pragma unroll
      for (int s = 0; s < 16; ++s) {
        const int e = e0 + ty*16 + s, d = d0 + tx;
        Q[(size_t)e * 16384 + jpar*256 + d] = tile[tx][ty*16 + s];
      }
    }
    return;
  }
  const int blk = blk0 - 2048;
  if (blk < 1152) {                                  // Qcat: 36x32 tiles of 64x64
    const int rt = blk >> 5, ct = blk & 31;
    const int k0 = rt * 64, c0 = ct * 64;
    const int r = c0 >> 8, d0 = c0 & 255;
    int p = 0, e0 = 0;
    bool zero = false;
    if (k0 < 256) { p = r; e0 = k0; }
    else {
      const int u = (k0 - 256) >> 8; e0 = (k0 - 256) & 255;
      if (u >= r) zero = true; else p = r - 1 - u;
    }
    if (zero) {
#pragma unroll
      for (int s = 0; s < 16; ++s)
        Qcat[(size_t)(k0 + ty*16 + s) * 2048 + c0 + tx] = 0;
      return;
    }
    const unsigned short* src = Phi2 + (size_t)p * 65536;
#pragma unroll
    for (int s = 0; s < 16; ++s)
      tile[ty*16 + s][tx] = src[(size_t)(d0 + ty*16 + s) * 256 + e0 + tx];
    __syncthreads();
#pragma unroll
    for (int s = 0; s < 16; ++s)
      Qcat[(size_t)(k0 + ty*16 + s) * 2048 + c0 + tx] = tile[tx][ty*16 + s];
  } else if (blk < 1280) {                           // G2: 32x4 tiles
    const int t = blk - 1152;
    const int rt = t >> 2, ct = t & 3;
    const int k0 = rt * 64, d0 = ct * 64;
    const int r = k0 >> 8, e0 = k0 & 255;
    const unsigned short* src = Phi2 + (size_t)(7 - r) * 65536;
#pragma unroll
    for (int s = 0; s < 16; ++s)
      tile[ty*16 + s][tx] = src[(size_t)(d0 + ty*16 + s) * 256 + e0 + tx];
    __syncthreads();
#pragma unroll
    for (int s = 0; s < 16; ++s)
      G2[(size_t)(k0 + ty*16 + s) * 256 + d0 + tx] = tile[tx][ty*16 + s];
  } else {                                           // LcT2 hi (16) + lo (16)
    const int t = blk - 1280;
    const int half = t >> 4, t16 = t & 15;
    const int d0 = (t16 & 3) * 64, e0 = (t16 >> 2) * 64;
    const unsigned short* src = (half ? Plo2 : Phi2) + (size_t)8 * 65536;
    unsigned short* dst = half ? LcT2lo : LcT2hi;
#pragma unroll
    for (int s = 0; s < 16; ++s)
      tile[ty*16 + s][tx] = src[(size_t)(d0 + ty*16 + s) * 256 + e0 + tx];
    __syncthreads();
#pragma unroll
    for (int s = 0; s < 16; ++s)
      dst[(size_t)(e0 + ty*16 + s) * 256 + d0 + tx] = tile[tx][ty*16 + s];
  }
}

// ---------------------------------------------------------------------------
// reduce split-K partials and scatter into Acat (bf16) S-region:
// s_{b, i=8m+u}[e] -> Acat[b*8+m][256 + u*256 + e]
// ---------------------------------------------------------------------------
__global__ __launch_bounds__(256) void reduce_s2(
    const float* __restrict__ Sp, unsigned short* __restrict__ Acat)
{
  const int f = blockIdx.x * 256 + threadIdx.x;   // 262144 total
  float v = 0;
#pragma unroll
  for (int z = 0; z < 8; ++z) v += Sp[(size_t)z * 262144 + f];
  const int e = f & 255, i = (f >> 8) & 63, b = f >> 14;
  const int u = i & 7, m = i >> 3;
  Acat[(size_t)(b*8 + m) * 2304 + 256 + u*256 + e] = f2u(v);
}

// ---------------------------------------------------------------------------
// Level-2 sequential combine: 8 steps, ONE workgroup, split-bf16 MFMA.
// A2_{b,m} (state entering superchunk m) written bf16 into Acat cols 0..255.
// ---------------------------------------------------------------------------
__global__ __launch_bounds__(512, 2) void k4b_combine(
    const unsigned short* __restrict__ LcT2hi, const unsigned short* __restrict__ LcT2lo,
    const float* __restrict__ S2, unsigned short* __restrict__ Acat)
{
  __shared__ unsigned short Hhi[16][264];
  __shared__ unsigned short Hlo[16][264];
  const int tid = threadIdx.x, lane = tid & 63, w = tid >> 6;  // 8 waves
  const int q = lane >> 4, ln = lane & 15;

  v8s bhi[8][2], blo[8][2];                       // (Lam^512)^T frags, cols [32w,32w+32)
#pragma unroll
  for (int kk = 0; kk < 8; ++kk)
#pragma unroll
    for (int nb = 0; nb < 2; ++nb) {
      const int n = 32*w + nb*16 + ln;
#pragma unroll
      for (int r = 0; r < 8; ++r) {
        const int k = kk*32 + q*8 + r;
        bhi[kk][nb][r] = (short)LcT2hi[k*256 + n];
        blo[kk][nb][r] = (short)LcT2lo[k*256 + n];
      }
    }
  for (int e = tid; e < 16*264; e += 512) { (&Hhi[0][0])[e] = 0; (&Hlo[0][0])[e] = 0; }
  lds_barrier();

  for (int m = 0; m < 8; ++m) {
    // A2_{b,m} = state BEFORE absorbing superchunk m
    for (int e = tid; e < 4096; e += 512) {
      const int b = e >> 8, d = e & 255;
      Acat[(size_t)(b*8 + m) * 2304 + d] = Hhi[b][d];
    }
    v8s ahi[8], alo[8];
#pragma unroll
    for (int kk = 0; kk < 8; ++kk) {
      ahi[kk] = *(const v8s*)&Hhi[ln][kk*32 + q*8];
      alo[kk] = *(const v8s*)&Hlo[ln][kk*32 + q*8];
    }
    lds_barrier();
    v4f acc[2];
#pragma unroll
    for (int nb = 0; nb < 2; ++nb)
#pragma unroll
      for (int r = 0; r < 4; ++r) {
        const int bb = 4*q + r, col = 32*w + nb*16 + ln;
        acc[nb][r] = S2[(size_t)(bb*8 + m) * 256 + col];
      }
#pragma unroll
    for (int kk = 0; kk < 8; ++kk)
#pragma unroll
      for (int nb = 0; nb < 2; ++nb) {
        acc[nb] = __builtin_amdgcn_mfma_f32_16x16x32_bf16(ahi[kk], bhi[kk][nb], acc[nb], 0, 0, 0);
        acc[nb] = __builtin_amdgcn_mfma_f32_16x16x32_bf16(alo[kk], bhi[kk][nb], acc[nb], 0, 0, 0);
        acc[nb] = __builtin_amdgcn_mfma_f32_16x16x32_bf16(ahi[kk], blo[kk][nb], acc[nb], 0, 0, 0);
      }
#pragma unroll
    for (int nb = 0; nb < 2; ++nb)
#pragma unroll
      for (int r = 0; r < 4; ++r) {
        const int bb = 4*q + r, col = 32*w + nb*16 + ln;
        float v = acc[nb][r];
        unsigned short hi = f2u(v);
        Hhi[bb][col] = hi;
        Hlo[bb][col] = f2u(v - u2f(hi));
      }
    lds_barrier();
  }
}

// ---------------------------------------------------------------------------
// Phase 3: local scan (init 0), writes g_local (fp32) to Out. Carry added
// later by the carry GEMM's += epilogue. Double-buffered state LDS -> ONE
// lds_barrier per step (R2 had two); Bx depth-2 register prefetch unchanged.
// 256 blocks x 4 chunk-states, 64 bf16-MFMA steps each. Bit-identical math.
// ---------------------------------------------------------------------------
__global__ __launch_bounds__(256, 1) void k5_scan(
    const unsigned short* __restrict__ LamT,
    const unsigned short* __restrict__ Bx, float* __restrict__ Out)
{
  __shared__ unsigned short gs[2][16][264];
  const int tid = threadIdx.x, lane = tid & 63, w = tid >> 6;  // 4 waves
  const int q = lane >> 4, ln = lane & 15;
  const int blk = blockIdx.x;
  const int b  = blk >> 4;            // batch
  const int i0 = (blk * 4) & 63;      // first chunk index of this block

  v8s bf[8][4];                        // Lam^T frags, cols [64w,64w+64)
#pragma unroll
  for (int kk = 0; kk < 8; ++kk)
#pragma unroll
    for (int nb = 0; nb < 4; ++nb) {
      const int n = 64*w + nb*16 + ln;
#pragma unroll
      for (int r = 0; r < 8; ++r)
        bf[kk][nb][r] = (short)LamT[(kk*32 + q*8 + r) * 256 + n];
    }
  for (int e = tid; e < 16*264; e += 256) (&gs[0][0][0])[e] = 0;  // zero buf 0

  size_t base[4];
#pragma unroll
  for (int r = 0; r < 4; ++r)
    base[r] = ((size_t)b*4096 + (size_t)(i0 + r)*64) * 256;   // row of step j=0
  const int colw = 64*w;

  unsigned short bxr[2][4][4];         // depth-2 Bx prefetch ring (q==0 lanes)
  if (q == 0) {
#pragma unroll
    for (int s = 0; s < 2; ++s)
#pragma unroll
      for (int r = 0; r < 4; ++r)
#pragma unroll
        for (int nb = 0; nb < 4; ++nb)
          bxr[s][r][nb] = Bx[base[r] + (size_t)s*256 + colw + nb*16 + ln];
  }
  lds_barrier();

#pragma unroll 2
  for (int j = 0; j < CHUNK; ++j) {
    // read state from buf j&1 (complete as of the barrier ending step j-1)
    v8s a[8];
#pragma unroll
    for (int kk = 0; kk < 8; ++kk) a[kk] = *(const v8s*)&gs[j & 1][ln][kk*32 + q*8];
    v4f acc[4];
#pragma unroll
    for (int nb = 0; nb < 4; ++nb) acc[nb] = 0;
#pragma unroll
    for (int kk = 0; kk < 8; ++kk)
#pragma unroll
      for (int nb = 0; nb < 4; ++nb)
        acc[nb] = __builtin_amdgcn_mfma_f32_16x16x32_bf16(a[kk], bf[kk][nb], acc[nb], 0, 0, 0);
    if (q == 0) {
#pragma unroll
      for (int r = 0; r < 4; ++r) {
        const size_t rb = base[r] + (size_t)j*256 + colw;
#pragma unroll
        for (int nb = 0; nb < 4; ++nb) {
          const float g = acc[nb][r] + u2f(bxr[j & 1][r][nb]);
          Out[rb + nb*16 + ln] = g;
          gs[(j + 1) & 1][r][colw + nb*16 + ln] = f2u(g);   // write OTHER buffer
        }
      }
      if (j < CHUNK - 2) {
#pragma unroll
        for (int r = 0; r < 4; ++r) {
          const size_t rb = base[r] + (size_t)(j + 2)*256 + colw;
#pragma unroll
          for (int nb = 0; nb < 4; ++nb)
            bxr[j & 1][r][nb] = Bx[rb + nb*16 + ln];
        }
      }
    }
    lds_barrier();   // single barrier: new state visible to all waves
  }
}

// ---------------------------------------------------------------------------
extern "C" void kernel_launch(void* const* d_in, const int* in_sizes, int n_in,
                              void* d_out, int out_size, void* d_ws, size_t ws_size,
                              hipStream_t stream)
{
  const float* x   = (const float*)d_in[0];
  const float* Bm  = (const float*)d_in[1];
  const float* Lam = (const float*)d_in[2];
  float* Out = (float*)d_out;
  (void)in_sizes; (void)n_in; (void)out_size; (void)ws_size;

  char* ws = (char*)d_ws;
  size_t off = 0;
  auto alloc = [&](size_t bytes) { void* p = ws + off; off += (bytes + 255) & ~(size_t)255; return p; };
  unsigned short* Bx    = (unsigned short*)alloc((size_t)16777216 * 2);      // 32 MB
  unsigned short* Phi   = (unsigned short*)alloc((size_t)65 * 65536 * 2);    // 8.3 MB
  unsigned short* Plo   = (unsigned short*)alloc((size_t)65 * 65536 * 2);    // 8.3 MB
  unsigned short* Ghat  = (unsigned short*)alloc((size_t)16384 * 256 * 2);   // 8 MB
  unsigned short* Q     = (unsigned short*)alloc((size_t)256 * 16384 * 2);   // 8 MB
  unsigned short* Qcat  = (unsigned short*)alloc((size_t)2304 * 2048 * 2);   // 9.4 MB
  unsigned short* G2    = (unsigned short*)alloc((size_t)2048 * 256 * 2);    // 1 MB
  unsigned short* Phi2  = (unsigned short*)alloc((size_t)9 * 65536 * 2);
  unsigned short* Plo2  = (unsigned short*)alloc((size_t)9 * 65536 * 2);
  unsigned short* Bt    = (unsigned short*)alloc(131072);
  unsigned short* LamT  = (unsigned short*)alloc(131072);
  unsigned short* LcT2hi= (unsigned short*)alloc(131072);
  unsigned short* LcT2lo= (unsigned short*)alloc(131072);
  unsigned short* Acat  = (unsigned short*)alloc((size_t)128 * 2304 * 2);    // 0.6 MB
  float*          S2    = (float*)alloc(131072);
  unsigned short* Abf   = (unsigned short*)alloc(524288);
  float*          Spart = (float*)Plo;  // alias: Plo dead before summary GEMM writes Spart

  // 1) packs + P0/P1
  pack_init<<<dim3(256), dim3(256), 0, stream>>>(Bm, Lam, Bt, LamT, Phi, Plo);
  // 2) Bx = x @ B^T  (bf16 out)
  gemm_tile<true, true, false><<<dim3(4, 1024, 1), dim3(256), 0, stream>>>(
      (const void*)x, Bt, (void*)Bx, 256, 256, 256, 256, 0);
  // 3) local scans: Out = g_local (fp32). Carry added later by GEMM epilogue.
  k5_scan<<<dim3(256), dim3(256), 0, stream>>>(LamT, Bx, Out);
  // 4) level-1 powers P_2..P_64 by doubling
  for (int mp = 1; mp <= 32; mp <<= 1)
    pow_round<<<dim3(mp * 4, 4, 1), dim3(256), 0, stream>>>(Phi, Plo, mp);
  // 5) level-2 power table P2_j = Lam^(64j), j=0..8
  pack2_init<<<dim3(256), dim3(256), 0, stream>>>(Phi, Plo, Phi2, Plo2);
  for (int mp = 1; mp <= 4; mp <<= 1)
    pow_round<<<dim3(mp * 4, 4, 1), dim3(256), 0, stream>>>(Phi2, Plo2, mp);
  // 6) pack all GEMM operands (fused)
  pack_all<<<dim3(3360), dim3(256), 0, stream>>>(Phi, Phi2, Plo2,
      Ghat, Q, Qcat, G2, LcT2hi, LcT2lo);
  // 7) chunk summaries: S = Bx_reshaped[1024,16384] @ Ghat  (split-K=8)
  gemm_tile<false, false, false><<<dim3(4, 16, 8), dim3(256), 0, stream>>>(
      (const void*)Bx, Ghat, (void*)Spart, 16384, 256, 256, 2048, 262144);
  reduce_s2<<<dim3(1024), dim3(256), 0, stream>>>(Spart, Acat);
  // 8) level-2 summaries: S2[128,256] = Acat_S[128,2048] @ G2
  gemm_tile<false, false, false><<<dim3(4, 2, 1), dim3(256), 0, stream>>>(
      (const void*)(Acat + 256), G2, (void*)S2, 2304, 256, 256, 2048, 0);
  // 9) sequential combine over 8 superchunks -> A2 into Acat cols 0..255
  k4b_combine<<<dim3(1), dim3(512), 0, stream>>>(LcT2hi, LcT2lo, S2, Acat);
  // 10) all chunk-entry states in one GEMM: Abf[128,2048] = Acat[128,2304] @ Qcat
  gemm_tile<false, true, false><<<dim3(32, 2, 1), dim3(256), 0, stream>>>(
      (const void*)Acat, Qcat, (void*)Abf, 2304, 2048, 2048, 2304, 0);
  // 11) carry GEMM with += epilogue: Out = Abf @ Q + Out(g_local)
  gemm_tile<false, false, true><<<dim3(256, 16, 1), dim3(256), 0, stream>>>(
      (const void*)Abf, Q, (void*)Out, 256, 16384, 16384, 256, 0);
}